// Round 6
// baseline (830.550 us; speedup 1.0000x reference)
//
#include <hip/hip_runtime.h>
#include <hip/hip_fp16.h>
#include <math.h>

#define NN 50000
#define NE 1600000
#define NBK 196          // buckets of 256 dst-nodes: cdiv(50000,256)
#define EPB 4096         // edges per block in bucket kernels

typedef unsigned int u32;

static inline int cdiv(int a, int b){ return (a + b - 1) / b; }

// ---------------- CSR build ----------------

__global__ void k_bcount(const int* __restrict__ dst, int* __restrict__ bcnt, int e){
  __shared__ int h[NBK];
  int t = threadIdx.x;
  for (int b = t; b < NBK; b += 256) h[b] = 0;
  __syncthreads();
  int beg = blockIdx.x*EPB, end = min(beg + EPB, e);
  for (int i = beg + t; i < end; i += 256) atomicAdd(&h[dst[i] >> 8], 1);
  __syncthreads();
  for (int b = t; b < NBK; b += 256) if (h[b]) atomicAdd(&bcnt[b], h[b]);
}

// single block: exclusive scan of bucket counts -> boff[0..NBK]; init bcur; row[n]=e
__global__ void k_scan_bcnt(const int* __restrict__ bcnt, int* __restrict__ boff,
                            int* __restrict__ bcur, int* __restrict__ row){
  __shared__ int sh[256];
  int t = threadIdx.x;
  int v = (t < NBK) ? bcnt[t] : 0;
  sh[t] = v; __syncthreads();
  for (int o = 1; o < 256; o <<= 1){
    int u = (t >= o) ? sh[t-o] : 0;
    __syncthreads();
    sh[t] += u;
    __syncthreads();
  }
  int ex = sh[t] - v;
  if (t <= NBK) boff[t] = ex;
  if (t <  NBK) bcur[t] = ex;
  if (t == 0)   row[NN] = NE;
}

// phase A: bin edges by dst>>8; pack dlow into src high bits (src < 65536)
__global__ void k_bucket(const int* __restrict__ src, const int* __restrict__ dst,
                         const float* __restrict__ ew, int* __restrict__ bcur,
                         int2* __restrict__ seL, int e){
  __shared__ int h[NBK], base[NBK], cur[NBK];
  int t = threadIdx.x;
  for (int b = t; b < NBK; b += 256){ h[b] = 0; cur[b] = 0; }
  __syncthreads();
  int beg = blockIdx.x*EPB, end = min(beg + EPB, e);
  for (int i = beg + t; i < end; i += 256) atomicAdd(&h[dst[i] >> 8], 1);
  __syncthreads();
  for (int b = t; b < NBK; b += 256)
    if (h[b] > 0) base[b] = atomicAdd(&bcur[b], h[b]);
  __syncthreads();
  for (int i = beg + t; i < end; i += 256){
    int d = dst[i], b = d >> 8;
    int pos = base[b] + atomicAdd(&cur[b], 1);
    seL[pos] = make_int2(((d & 255) << 16) | src[i], __float_as_int(ew[i]));
  }
}

// phase B: one block per bucket; per-node hist+scan+scatter+deg in LDS.
// packed entry: lo16 = src, hi16 = fp16 edge weight (later overwritten by norm).
__global__ void k_csr_bucket(const int* __restrict__ boff, const int2* __restrict__ seL,
                             int* __restrict__ row, u32* __restrict__ packed,
                             float* __restrict__ dinv, int n){
  __shared__ int hist[256], sh[256], cur[256];
  __shared__ float wsum[256];
  int b = blockIdx.x, t = threadIdx.x;
  int ebeg = boff[b], eend = boff[b+1];
  hist[t] = 0; wsum[t] = 0.f;
  __syncthreads();
  for (int i = ebeg + t; i < eend; i += 256)
    atomicAdd(&hist[seL[i].x >> 16], 1);
  __syncthreads();
  int v = hist[t];
  sh[t] = v; __syncthreads();
  for (int o = 1; o < 256; o <<= 1){
    int u = (t >= o) ? sh[t-o] : 0;
    __syncthreads();
    sh[t] += u;
    __syncthreads();
  }
  int rowv = ebeg + sh[t] - v;
  int node = b*256 + t;
  if (node < n) row[node] = rowv;
  cur[t] = rowv;
  __syncthreads();
  for (int i = ebeg + t; i < eend; i += 256){
    int2 u = seL[i];
    int d = u.x >> 16;
    int pos = atomicAdd(&cur[d], 1);
    float w = __int_as_float(u.y);
    packed[pos] = (u32)(u.x & 0xFFFF) |
                  ((u32)__half_as_ushort(__float2half(w)) << 16);
    atomicAdd(&wsum[d], w);
  }
  __syncthreads();
  if (node < n) dinv[node] = rsqrtf(1.f + wsum[t]);   // deg >= 1 (self-loop)
}

// one wave per node: hi16 of packed := fp16( ew * dinv[src] * dinv[node] )
__global__ void k_nrm(const int* __restrict__ row, u32* __restrict__ packed,
                      const float* __restrict__ dinv, int n){
  int tid = blockIdx.x*256 + threadIdx.x;
  int node = tid >> 6, lane = tid & 63;
  if (node >= n) return;
  float di = dinv[node];
  int beg = row[node], end = row[node+1];
  for (int p = beg + lane; p < end; p += 64){
    u32 v = packed[p];
    int s = v & 0xFFFF;
    float w = __half2float(__ushort_as_half((unsigned short)(v >> 16)));
    w *= di * dinv[s];
    packed[p] = (v & 0xFFFFu) | ((u32)__half_as_ushort(__float2half(w)) << 16);
  }
}

// ---------------- dense transforms (W in VGPRs, multi-node waves) ----------------

// fp32 input [n,FIN] -> fp16 half-split out xwh[2][n][32]; no activation
template<int FIN>
__global__ void k_xform64f(const float* __restrict__ in, const float* __restrict__ W,
                           __half* __restrict__ out, int n){
  int j = threadIdx.x & 63;
  int wid = (blockIdx.x*256 + threadIdx.x) >> 6;
  int nw = gridDim.x * 4;
  float wreg[FIN];
  #pragma unroll
  for (int k = 0; k < FIN; ++k) wreg[k] = W[k*64 + j];   // coalesced, once per wave
  size_t outoff = (size_t)(j >> 5)*(size_t)n*32 + (j & 31);
  for (int node = wid; node < n; node += nw){
    const float* r = in + (size_t)node*FIN;
    float acc = 0.f;
    #pragma unroll
    for (int k = 0; k < FIN; ++k) acc = fmaf(r[k], wreg[k], acc);
    out[outoff + (size_t)node*32] = __float2half(acc);
  }
}

// fp16 input [n,64] -> relu -> @W[64,64] -> fp16 half-split out
__global__ void k_xform64h(const __half* __restrict__ in, const float* __restrict__ W,
                           __half* __restrict__ out, int n){
  int j = threadIdx.x & 63;
  int wid = (blockIdx.x*256 + threadIdx.x) >> 6;
  int nw = gridDim.x * 4;
  float wreg[64];
  #pragma unroll
  for (int k = 0; k < 64; ++k) wreg[k] = W[k*64 + j];
  size_t outoff = (size_t)(j >> 5)*(size_t)n*32 + (j & 31);
  for (int node = wid; node < n; node += nw){
    const float4* r4 = (const float4*)(in + (size_t)node*64);
    float acc = 0.f;
    #pragma unroll
    for (int q = 0; q < 8; ++q){
      float4 c = r4[q];                      // broadcast 16B = 8 fp16
      const __half2* h2 = (const __half2*)&c;
      #pragma unroll
      for (int t = 0; t < 4; ++t){
        float2 f2 = __half22float2(h2[t]);
        acc = fmaf(fmaxf(f2.x, 0.f), wreg[q*8 + 2*t    ], acc);
        acc = fmaf(fmaxf(f2.y, 0.f), wreg[q*8 + 2*t + 1], acc);
      }
    }
    out[outoff + (size_t)node*32] = __float2half(acc);
  }
}

// fp16 input [n,64] -> relu -> @W[64,1] -> fp32 out[n]; wave per node, lane-parallel
__global__ void k_xform1h(const __half* __restrict__ in, const float* __restrict__ W,
                          float* __restrict__ out, int n){
  int tid = blockIdx.x*256 + threadIdx.x;
  int node = tid >> 6, lane = tid & 63;
  if (node >= n) return;
  float w = W[lane];
  float v = fmaxf(__half2float(in[(size_t)node*64 + lane]), 0.f) * w;
  for (int o = 32; o > 0; o >>= 1) v += __shfl_xor(v, o, 64);
  if (lane == 0) out[node] = v;
}

// ---------------- CSR aggregation: feature-half passes in one launch ----------------

// one wave per node per half; lanes 0-31 even edge, 32-63 odd edge.
// metadata: one u32/lane per 64 edges; gather working set 3.2MB < 4MiB L2.
__global__ void k_agg64h(const int* __restrict__ row, const u32* __restrict__ packed,
                         const __half* __restrict__ xw, const float* __restrict__ dinv,
                         const float* __restrict__ b, __half* __restrict__ out,
                         int n, int gw){
  int blk = blockIdx.x;
  int pass = (blk >= gw) ? 1 : 0;
  if (pass) blk -= gw;
  int tid = blk*256 + threadIdx.x;
  int node = tid >> 6, lane = tid & 63;
  if (node >= n) return;
  int f = lane & 31, ep = lane >> 5;
  const __half* xh = xw + (size_t)pass*(size_t)n*32;
  float acc = 0.f;
  int p = row[node], end = row[node+1];
  for (; p + 64 <= end; p += 64){
    u32 myv = __builtin_nontemporal_load(&packed[p + lane]);   // 64 edges
    #pragma unroll
    for (int t = 0; t < 32; ++t){
      u32 v0 = __builtin_amdgcn_readlane(myv, 2*t);
      u32 v1 = __builtin_amdgcn_readlane(myv, 2*t + 1);
      u32 v = ep ? v1 : v0;
      int s = v & 0xFFFF;
      float w = __half2float(__ushort_as_half((unsigned short)(v >> 16)));
      acc = fmaf(w, __half2float(xh[s*32 + f]), acc);
    }
  }
  int rem = end - p;
  if (rem > 0){
    u32 myv = (lane < rem) ? packed[p + lane] : 0u;   // pad edges: w=0 -> harmless
    int it = (rem + 1) >> 1;
    for (int t = 0; t < it; ++t){
      u32 v0 = __builtin_amdgcn_readlane(myv, 2*t);
      u32 v1 = __builtin_amdgcn_readlane(myv, 2*t + 1);
      u32 v = ep ? v1 : v0;
      int s = v & 0xFFFF;
      float w = __half2float(__ushort_as_half((unsigned short)(v >> 16)));
      acc = fmaf(w, __half2float(xh[s*32 + f]), acc);
    }
  }
  acc += __shfl_xor(acc, 32, 64);                    // combine even/odd partials
  if (ep == 0){
    float di = dinv[node];
    float tot = acc + __half2float(xh[(size_t)node*32 + f])*(di*di) + b[pass*32 + f];
    out[(size_t)node*64 + pass*32 + f] = __float2half(tot);
  }
}

// scalar agg (wave per node) + Linear(1,1) + build xin = cat(x, xsol)
__global__ void k_agg1_xsol(const int* __restrict__ row, const u32* __restrict__ packed,
                            const float* __restrict__ s0, const float* __restrict__ dinv,
                            const float* __restrict__ b, const float* __restrict__ Wl,
                            const float* __restrict__ bl, const float* __restrict__ x,
                            float* __restrict__ xsol, float* __restrict__ xin, int n){
  int tid = blockIdx.x*256 + threadIdx.x;
  int node = tid >> 6, lane = tid & 63;
  if (node >= n) return;
  int beg = row[node], end = row[node+1];
  float acc = 0.f;
  for (int p = beg + lane; p < end; p += 64){
    u32 v = packed[p];
    float w = __half2float(__ushort_as_half((unsigned short)(v >> 16)));
    acc = fmaf(w, s0[v & 0xFFFF], acc);
  }
  for (int o = 32; o > 0; o >>= 1) acc += __shfl_xor(acc, o, 64);
  if (lane == 0){
    float di = dinv[node];
    float v = s0[node]*(di*di) + b[0] + acc;
    v = v*Wl[0] + bl[0];
    xsol[node] = v;
    float4 xv = ((const float4*)x)[node];
    xin[node*5+0] = xv.x;
    xin[node*5+1] = xv.y;
    xin[node*5+2] = xv.z;
    xin[node*5+3] = xv.w;
    xin[node*5+4] = v;
  }
}

// scalar agg + Linear(1,1) + sigmoid + gated residual combine
__global__ void k_agg1_final(const int* __restrict__ row, const u32* __restrict__ packed,
                             const float* __restrict__ s0, const float* __restrict__ dinv,
                             const float* __restrict__ b, const float* __restrict__ Wl,
                             const float* __restrict__ bl, const float* __restrict__ xsol,
                             const float* __restrict__ x, float* __restrict__ out, int n){
  int tid = blockIdx.x*256 + threadIdx.x;
  int node = tid >> 6, lane = tid & 63;
  if (node >= n) return;
  int beg = row[node], end = row[node+1];
  float acc = 0.f;
  for (int p = beg + lane; p < end; p += 64){
    u32 v = packed[p];
    float w = __half2float(__ushort_as_half((unsigned short)(v >> 16)));
    acc = fmaf(w, s0[v & 0xFFFF], acc);
  }
  for (int o = 32; o > 0; o >>= 1) acc += __shfl_xor(acc, o, 64);
  if (lane == 0){
    float di = dinv[node];
    float g = s0[node]*(di*di) + b[0] + acc;
    g = g*Wl[0] + bl[0];
    float gamma = 1.f / (1.f + expf(-g));
    float xl = x[node*4+3];
    out[node]     = xl + gamma*(xsol[node] - xl);
    out[n + node] = gamma;
  }
}

// ---------------- launch ----------------

extern "C" void kernel_launch(void* const* d_in, const int* in_sizes, int n_in,
                              void* d_out, int out_size, void* d_ws, size_t ws_size,
                              hipStream_t stream){
  const float* x   = (const float*)d_in[0];
  const int*   ei  = (const int*)d_in[1];
  const float* ew  = (const float*)d_in[2];
  const float* oW0 = (const float*)d_in[3];
  const float* ob0 = (const float*)d_in[4];
  const float* oW1 = (const float*)d_in[5];
  const float* ob1 = (const float*)d_in[6];
  const float* oW2 = (const float*)d_in[7];
  const float* ob2 = (const float*)d_in[8];
  const float* oWl = (const float*)d_in[9];
  const float* obl = (const float*)d_in[10];
  const float* gW0 = (const float*)d_in[11];
  const float* gb0 = (const float*)d_in[12];
  const float* gW1 = (const float*)d_in[13];
  const float* gb1 = (const float*)d_in[14];
  const float* gW2 = (const float*)d_in[15];
  const float* gb2 = (const float*)d_in[16];
  const float* gWl = (const float*)d_in[17];
  const float* gbl = (const float*)d_in[18];

  const int n = NN, e = NE;
  const int* src = ei;
  const int* dst = ei + e;

  // workspace layout (8B-aligned blocks first)
  char* wsb = (char*)d_ws;
  int2*  seL    = (int2*)wsb;      wsb += (size_t)e*sizeof(int2);      // 12.8 MB
  u32*   packed = (u32*)wsb;       wsb += (size_t)e*4;                 // 6.4 MB
  __half* bufA  = (__half*)wsb;    wsb += (size_t)n*64*2;              // 6.4 MB (xwh[2][n][32])
  __half* bufB  = (__half*)wsb;    wsb += (size_t)n*64*2;              // 6.4 MB ([n][64])
  int*   row    = (int*)wsb;       wsb += (size_t)(n+1)*4;
  int*   bcnt   = (int*)wsb;       wsb += 256*4;
  int*   boff   = (int*)wsb;       wsb += 256*4;
  int*   bcur   = (int*)wsb;       wsb += 256*4;
  float* dinv   = (float*)wsb;     wsb += (size_t)n*4;
  float* s0     = (float*)wsb;     wsb += (size_t)n*4;
  float* xsol   = (float*)wsb;     wsb += (size_t)n*4;
  float* xin    = (float*)wsb;     wsb += (size_t)n*5*4;

  dim3 b256(256);
  int gn = cdiv(n, 256);           // 196
  int gw = cdiv(n*64, 256);        // 12500 (wave-per-node kernels)
  int gb = cdiv(e, EPB);           // 391
  int gx = 512;                    // multi-node-wave transform grids
  int gx64 = 1024;

  // ---- CSR build + normalization (shared by all 6 convs) ----
  hipMemsetAsync(bcnt, 0, 256*4, stream);
  k_bcount    <<<gb,  b256, 0, stream>>>(dst, bcnt, e);
  k_scan_bcnt <<<1,   b256, 0, stream>>>(bcnt, boff, bcur, row);
  k_bucket    <<<gb,  b256, 0, stream>>>(src, dst, ew, bcur, seL, e);
  k_csr_bucket<<<NBK, b256, 0, stream>>>(boff, seL, row, packed, dinv, n);
  k_nrm       <<<gw,  b256, 0, stream>>>(row, packed, dinv, n);

  // ---- optim tower: 4 -> 64 -> 64 -> 1, Linear(1,1) ----
  k_xform64f<4><<<gx,   b256, 0, stream>>>(x, oW0, bufA, n);
  k_agg64h     <<<2*gw, b256, 0, stream>>>(row, packed, bufA, dinv, ob0, bufB, n, gw);
  k_xform64h   <<<gx64, b256, 0, stream>>>(bufB, oW1, bufA, n);
  k_agg64h     <<<2*gw, b256, 0, stream>>>(row, packed, bufA, dinv, ob1, bufB, n, gw);
  k_xform1h    <<<gw,   b256, 0, stream>>>(bufB, oW2, s0, n);
  k_agg1_xsol  <<<gw,   b256, 0, stream>>>(row, packed, s0, dinv, ob2, oWl, obl, x, xsol, xin, n);

  // ---- gamma tower: 5 -> 64 -> 64 -> 1, Linear(1,1), sigmoid ----
  k_xform64f<5><<<gx,   b256, 0, stream>>>(xin, gW0, bufA, n);
  k_agg64h     <<<2*gw, b256, 0, stream>>>(row, packed, bufA, dinv, gb0, bufB, n, gw);
  k_xform64h   <<<gx64, b256, 0, stream>>>(bufB, gW1, bufA, n);
  k_agg64h     <<<2*gw, b256, 0, stream>>>(row, packed, bufA, dinv, gb1, bufB, n, gw);
  k_xform1h    <<<gw,   b256, 0, stream>>>(bufB, gW2, s0, n);
  k_agg1_final <<<gw,   b256, 0, stream>>>(row, packed, s0, dinv, gb2, gWl, gbl, xsol, x, (float*)d_out, n);
}

// Round 7
// 825.109 us; speedup vs baseline: 1.0066x; 1.0066x over previous
//
#include <hip/hip_runtime.h>
#include <hip/hip_fp16.h>
#include <math.h>

#define NN 50000
#define NE 1600000
#define NBK 196          // buckets of 256 dst-nodes: cdiv(50000,256)
#define EPB 4096         // edges per block in bucket kernels

typedef unsigned int u32;

static inline int cdiv(int a, int b){ return (a + b - 1) / b; }

// ---------------- CSR build ----------------

__global__ void k_bcount(const int* __restrict__ dst, int* __restrict__ bcnt, int e){
  __shared__ int h[NBK];
  int t = threadIdx.x;
  for (int b = t; b < NBK; b += 256) h[b] = 0;
  __syncthreads();
  int beg = blockIdx.x*EPB, end = min(beg + EPB, e);
  for (int i = beg + t; i < end; i += 256) atomicAdd(&h[dst[i] >> 8], 1);
  __syncthreads();
  for (int b = t; b < NBK; b += 256) if (h[b]) atomicAdd(&bcnt[b], h[b]);
}

// single block: exclusive scan of bucket counts -> boff[0..NBK]; init bcur; row[n]=e
__global__ void k_scan_bcnt(const int* __restrict__ bcnt, int* __restrict__ boff,
                            int* __restrict__ bcur, int* __restrict__ row){
  __shared__ int sh[256];
  int t = threadIdx.x;
  int v = (t < NBK) ? bcnt[t] : 0;
  sh[t] = v; __syncthreads();
  for (int o = 1; o < 256; o <<= 1){
    int u = (t >= o) ? sh[t-o] : 0;
    __syncthreads();
    sh[t] += u;
    __syncthreads();
  }
  int ex = sh[t] - v;
  if (t <= NBK) boff[t] = ex;
  if (t <  NBK) bcur[t] = ex;
  if (t == 0)   row[NN] = NE;
}

// phase A: bin edges by dst>>8; pack dlow into src high bits (src < 65536)
__global__ void k_bucket(const int* __restrict__ src, const int* __restrict__ dst,
                         const float* __restrict__ ew, int* __restrict__ bcur,
                         int2* __restrict__ seL, int e){
  __shared__ int h[NBK], base[NBK], cur[NBK];
  int t = threadIdx.x;
  for (int b = t; b < NBK; b += 256){ h[b] = 0; cur[b] = 0; }
  __syncthreads();
  int beg = blockIdx.x*EPB, end = min(beg + EPB, e);
  for (int i = beg + t; i < end; i += 256) atomicAdd(&h[dst[i] >> 8], 1);
  __syncthreads();
  for (int b = t; b < NBK; b += 256)
    if (h[b] > 0) base[b] = atomicAdd(&bcur[b], h[b]);
  __syncthreads();
  for (int i = beg + t; i < end; i += 256){
    int d = dst[i], b = d >> 8;
    int pos = base[b] + atomicAdd(&cur[b], 1);
    seL[pos] = make_int2(((d & 255) << 16) | src[i], __float_as_int(ew[i]));
  }
}

// phase B: one block per bucket; per-node hist+scan+scatter+deg in LDS.
// packed entry: lo16 = src, hi16 = fp16 edge weight (later overwritten by norm).
__global__ void k_csr_bucket(const int* __restrict__ boff, const int2* __restrict__ seL,
                             int* __restrict__ row, u32* __restrict__ packed,
                             float* __restrict__ dinv, int n){
  __shared__ int hist[256], sh[256], cur[256];
  __shared__ float wsum[256];
  int b = blockIdx.x, t = threadIdx.x;
  int ebeg = boff[b], eend = boff[b+1];
  hist[t] = 0; wsum[t] = 0.f;
  __syncthreads();
  for (int i = ebeg + t; i < eend; i += 256)
    atomicAdd(&hist[seL[i].x >> 16], 1);
  __syncthreads();
  int v = hist[t];
  sh[t] = v; __syncthreads();
  for (int o = 1; o < 256; o <<= 1){
    int u = (t >= o) ? sh[t-o] : 0;
    __syncthreads();
    sh[t] += u;
    __syncthreads();
  }
  int rowv = ebeg + sh[t] - v;
  int node = b*256 + t;
  if (node < n) row[node] = rowv;
  cur[t] = rowv;
  __syncthreads();
  for (int i = ebeg + t; i < eend; i += 256){
    int2 u = seL[i];
    int d = u.x >> 16;
    int pos = atomicAdd(&cur[d], 1);
    float w = __int_as_float(u.y);
    packed[pos] = (u32)(u.x & 0xFFFF) |
                  ((u32)__half_as_ushort(__float2half(w)) << 16);
    atomicAdd(&wsum[d], w);
  }
  __syncthreads();
  if (node < n) dinv[node] = rsqrtf(1.f + wsum[t]);   // deg >= 1 (self-loop)
}

// one wave per node: hi16 of packed := fp16( ew * dinv[src] * dinv[node] )
__global__ void k_nrm(const int* __restrict__ row, u32* __restrict__ packed,
                      const float* __restrict__ dinv, int n){
  int tid = blockIdx.x*256 + threadIdx.x;
  int node = tid >> 6, lane = tid & 63;
  if (node >= n) return;
  float di = dinv[node];
  int beg = row[node], end = row[node+1];
  for (int p = beg + lane; p < end; p += 64){
    u32 v = packed[p];
    int s = v & 0xFFFF;
    float w = __half2float(__ushort_as_half((unsigned short)(v >> 16)));
    w *= di * dinv[s];
    packed[p] = (v & 0xFFFFu) | ((u32)__half_as_ushort(__float2half(w)) << 16);
  }
}

// ---------------- dense transforms (W in VGPRs, multi-node waves) ----------------
// __launch_bounds__(256, 4): 4 waves/SIMD -> 128-VGPR budget -> wreg[] stays in
// registers (r6's default 64-VGPR cap spilled wreg[64] to scratch: 185MB fetch)

// fp32 input [n,FIN] -> fp16 half-split out xwh[2][n][32]; no activation
template<int FIN>
__global__ __launch_bounds__(256, 4)
void k_xform64f(const float* __restrict__ in, const float* __restrict__ W,
                __half* __restrict__ out, int n){
  int j = threadIdx.x & 63;
  int wid = (blockIdx.x*256 + threadIdx.x) >> 6;
  int nw = gridDim.x * 4;
  float wreg[FIN];
  #pragma unroll
  for (int k = 0; k < FIN; ++k) wreg[k] = W[k*64 + j];   // coalesced, once per wave
  size_t outoff = (size_t)(j >> 5)*(size_t)n*32 + (j & 31);
  for (int node = wid; node < n; node += nw){
    const float* r = in + (size_t)node*FIN;
    float acc = 0.f;
    #pragma unroll
    for (int k = 0; k < FIN; ++k) acc = fmaf(r[k], wreg[k], acc);
    out[outoff + (size_t)node*32] = __float2half(acc);
  }
}

// fp16 input [n,64] -> relu -> @W[64,64] -> fp16 half-split out
__global__ __launch_bounds__(256, 4)
void k_xform64h(const __half* __restrict__ in, const float* __restrict__ W,
                __half* __restrict__ out, int n){
  int j = threadIdx.x & 63;
  int wid = (blockIdx.x*256 + threadIdx.x) >> 6;
  int nw = gridDim.x * 4;
  float wreg[64];
  #pragma unroll
  for (int k = 0; k < 64; ++k) wreg[k] = W[k*64 + j];
  size_t outoff = (size_t)(j >> 5)*(size_t)n*32 + (j & 31);
  for (int node = wid; node < n; node += nw){
    const float4* r4 = (const float4*)(in + (size_t)node*64);
    float acc = 0.f;
    #pragma unroll
    for (int q = 0; q < 8; ++q){
      float4 c = r4[q];                      // broadcast 16B = 8 fp16
      const __half2* h2 = (const __half2*)&c;
      #pragma unroll
      for (int t = 0; t < 4; ++t){
        float2 f2 = __half22float2(h2[t]);
        acc = fmaf(fmaxf(f2.x, 0.f), wreg[q*8 + 2*t    ], acc);
        acc = fmaf(fmaxf(f2.y, 0.f), wreg[q*8 + 2*t + 1], acc);
      }
    }
    out[outoff + (size_t)node*32] = __float2half(acc);
  }
}

// fp16 input [n,64] -> relu -> @W[64,1] -> fp32 out[n]; wave per node, lane-parallel
__global__ void k_xform1h(const __half* __restrict__ in, const float* __restrict__ W,
                          float* __restrict__ out, int n){
  int tid = blockIdx.x*256 + threadIdx.x;
  int node = tid >> 6, lane = tid & 63;
  if (node >= n) return;
  float w = W[lane];
  float v = fmaxf(__half2float(in[(size_t)node*64 + lane]), 0.f) * w;
  for (int o = 32; o > 0; o >>= 1) v += __shfl_xor(v, o, 64);
  if (lane == 0) out[node] = v;
}

// ---------------- CSR aggregation: feature-half passes in one launch ----------------

// one wave per node per half; lanes 0-31 even edge, 32-63 odd edge.
// metadata: one u32/lane per 64 edges; gather working set 3.2MB < 4MiB L2.
__global__ void k_agg64h(const int* __restrict__ row, const u32* __restrict__ packed,
                         const __half* __restrict__ xw, const float* __restrict__ dinv,
                         const float* __restrict__ b, __half* __restrict__ out,
                         int n, int gw){
  int blk = blockIdx.x;
  int pass = (blk >= gw) ? 1 : 0;
  if (pass) blk -= gw;
  int tid = blk*256 + threadIdx.x;
  int node = tid >> 6, lane = tid & 63;
  if (node >= n) return;
  int f = lane & 31, ep = lane >> 5;
  const __half* xh = xw + (size_t)pass*(size_t)n*32;
  float acc = 0.f;
  int p = row[node], end = row[node+1];
  for (; p + 64 <= end; p += 64){
    u32 myv = __builtin_nontemporal_load(&packed[p + lane]);   // 64 edges
    #pragma unroll
    for (int t = 0; t < 32; ++t){
      u32 v0 = __builtin_amdgcn_readlane(myv, 2*t);
      u32 v1 = __builtin_amdgcn_readlane(myv, 2*t + 1);
      u32 v = ep ? v1 : v0;
      int s = v & 0xFFFF;
      float w = __half2float(__ushort_as_half((unsigned short)(v >> 16)));
      acc = fmaf(w, __half2float(xh[s*32 + f]), acc);
    }
  }
  int rem = end - p;
  if (rem > 0){
    u32 myv = (lane < rem) ? packed[p + lane] : 0u;   // pad edges: w=0 -> harmless
    int it = (rem + 1) >> 1;
    for (int t = 0; t < it; ++t){
      u32 v0 = __builtin_amdgcn_readlane(myv, 2*t);
      u32 v1 = __builtin_amdgcn_readlane(myv, 2*t + 1);
      u32 v = ep ? v1 : v0;
      int s = v & 0xFFFF;
      float w = __half2float(__ushort_as_half((unsigned short)(v >> 16)));
      acc = fmaf(w, __half2float(xh[s*32 + f]), acc);
    }
  }
  acc += __shfl_xor(acc, 32, 64);                    // combine even/odd partials
  if (ep == 0){
    float di = dinv[node];
    float tot = acc + __half2float(xh[(size_t)node*32 + f])*(di*di) + b[pass*32 + f];
    out[(size_t)node*64 + pass*32 + f] = __float2half(tot);
  }
}

// scalar agg (wave per node) + Linear(1,1) + build xin = cat(x, xsol)
__global__ void k_agg1_xsol(const int* __restrict__ row, const u32* __restrict__ packed,
                            const float* __restrict__ s0, const float* __restrict__ dinv,
                            const float* __restrict__ b, const float* __restrict__ Wl,
                            const float* __restrict__ bl, const float* __restrict__ x,
                            float* __restrict__ xsol, float* __restrict__ xin, int n){
  int tid = blockIdx.x*256 + threadIdx.x;
  int node = tid >> 6, lane = tid & 63;
  if (node >= n) return;
  int beg = row[node], end = row[node+1];
  float acc = 0.f;
  for (int p = beg + lane; p < end; p += 64){
    u32 v = packed[p];
    float w = __half2float(__ushort_as_half((unsigned short)(v >> 16)));
    acc = fmaf(w, s0[v & 0xFFFF], acc);
  }
  for (int o = 32; o > 0; o >>= 1) acc += __shfl_xor(acc, o, 64);
  if (lane == 0){
    float di = dinv[node];
    float v = s0[node]*(di*di) + b[0] + acc;
    v = v*Wl[0] + bl[0];
    xsol[node] = v;
    float4 xv = ((const float4*)x)[node];
    xin[node*5+0] = xv.x;
    xin[node*5+1] = xv.y;
    xin[node*5+2] = xv.z;
    xin[node*5+3] = xv.w;
    xin[node*5+4] = v;
  }
}

// scalar agg + Linear(1,1) + sigmoid + gated residual combine
__global__ void k_agg1_final(const int* __restrict__ row, const u32* __restrict__ packed,
                             const float* __restrict__ s0, const float* __restrict__ dinv,
                             const float* __restrict__ b, const float* __restrict__ Wl,
                             const float* __restrict__ bl, const float* __restrict__ xsol,
                             const float* __restrict__ x, float* __restrict__ out, int n){
  int tid = blockIdx.x*256 + threadIdx.x;
  int node = tid >> 6, lane = tid & 63;
  if (node >= n) return;
  int beg = row[node], end = row[node+1];
  float acc = 0.f;
  for (int p = beg + lane; p < end; p += 64){
    u32 v = packed[p];
    float w = __half2float(__ushort_as_half((unsigned short)(v >> 16)));
    acc = fmaf(w, s0[v & 0xFFFF], acc);
  }
  for (int o = 32; o > 0; o >>= 1) acc += __shfl_xor(acc, o, 64);
  if (lane == 0){
    float di = dinv[node];
    float g = s0[node]*(di*di) + b[0] + acc;
    g = g*Wl[0] + bl[0];
    float gamma = 1.f / (1.f + expf(-g));
    float xl = x[node*4+3];
    out[node]     = xl + gamma*(xsol[node] - xl);
    out[n + node] = gamma;
  }
}

// ---------------- launch ----------------

extern "C" void kernel_launch(void* const* d_in, const int* in_sizes, int n_in,
                              void* d_out, int out_size, void* d_ws, size_t ws_size,
                              hipStream_t stream){
  const float* x   = (const float*)d_in[0];
  const int*   ei  = (const int*)d_in[1];
  const float* ew  = (const float*)d_in[2];
  const float* oW0 = (const float*)d_in[3];
  const float* ob0 = (const float*)d_in[4];
  const float* oW1 = (const float*)d_in[5];
  const float* ob1 = (const float*)d_in[6];
  const float* oW2 = (const float*)d_in[7];
  const float* ob2 = (const float*)d_in[8];
  const float* oWl = (const float*)d_in[9];
  const float* obl = (const float*)d_in[10];
  const float* gW0 = (const float*)d_in[11];
  const float* gb0 = (const float*)d_in[12];
  const float* gW1 = (const float*)d_in[13];
  const float* gb1 = (const float*)d_in[14];
  const float* gW2 = (const float*)d_in[15];
  const float* gb2 = (const float*)d_in[16];
  const float* gWl = (const float*)d_in[17];
  const float* gbl = (const float*)d_in[18];

  const int n = NN, e = NE;
  const int* src = ei;
  const int* dst = ei + e;

  // workspace layout (8B-aligned blocks first)
  char* wsb = (char*)d_ws;
  int2*  seL    = (int2*)wsb;      wsb += (size_t)e*sizeof(int2);      // 12.8 MB
  u32*   packed = (u32*)wsb;       wsb += (size_t)e*4;                 // 6.4 MB
  __half* bufA  = (__half*)wsb;    wsb += (size_t)n*64*2;              // 6.4 MB (xwh[2][n][32])
  __half* bufB  = (__half*)wsb;    wsb += (size_t)n*64*2;              // 6.4 MB ([n][64])
  int*   row    = (int*)wsb;       wsb += (size_t)(n+1)*4;
  int*   bcnt   = (int*)wsb;       wsb += 256*4;
  int*   boff   = (int*)wsb;       wsb += 256*4;
  int*   bcur   = (int*)wsb;       wsb += 256*4;
  float* dinv   = (float*)wsb;     wsb += (size_t)n*4;
  float* s0     = (float*)wsb;     wsb += (size_t)n*4;
  float* xsol   = (float*)wsb;     wsb += (size_t)n*4;
  float* xin    = (float*)wsb;     wsb += (size_t)n*5*4;

  dim3 b256(256);
  int gn = cdiv(n, 256);           // 196
  int gw = cdiv(n*64, 256);        // 12500 (wave-per-node kernels)
  int gb = cdiv(e, EPB);           // 391
  int gx = 512;                    // multi-node-wave transform grids
  int gx64 = 1024;

  // ---- CSR build + normalization (shared by all 6 convs) ----
  hipMemsetAsync(bcnt, 0, 256*4, stream);
  k_bcount    <<<gb,  b256, 0, stream>>>(dst, bcnt, e);
  k_scan_bcnt <<<1,   b256, 0, stream>>>(bcnt, boff, bcur, row);
  k_bucket    <<<gb,  b256, 0, stream>>>(src, dst, ew, bcur, seL, e);
  k_csr_bucket<<<NBK, b256, 0, stream>>>(boff, seL, row, packed, dinv, n);
  k_nrm       <<<gw,  b256, 0, stream>>>(row, packed, dinv, n);

  // ---- optim tower: 4 -> 64 -> 64 -> 1, Linear(1,1) ----
  k_xform64f<4><<<gx,   b256, 0, stream>>>(x, oW0, bufA, n);
  k_agg64h     <<<2*gw, b256, 0, stream>>>(row, packed, bufA, dinv, ob0, bufB, n, gw);
  k_xform64h   <<<gx64, b256, 0, stream>>>(bufB, oW1, bufA, n);
  k_agg64h     <<<2*gw, b256, 0, stream>>>(row, packed, bufA, dinv, ob1, bufB, n, gw);
  k_xform1h    <<<gw,   b256, 0, stream>>>(bufB, oW2, s0, n);
  k_agg1_xsol  <<<gw,   b256, 0, stream>>>(row, packed, s0, dinv, ob2, oWl, obl, x, xsol, xin, n);

  // ---- gamma tower: 5 -> 64 -> 64 -> 1, Linear(1,1), sigmoid ----
  k_xform64f<5><<<gx,   b256, 0, stream>>>(xin, gW0, bufA, n);
  k_agg64h     <<<2*gw, b256, 0, stream>>>(row, packed, bufA, dinv, gb0, bufB, n, gw);
  k_xform64h   <<<gx64, b256, 0, stream>>>(bufB, gW1, bufA, n);
  k_agg64h     <<<2*gw, b256, 0, stream>>>(row, packed, bufA, dinv, gb1, bufB, n, gw);
  k_xform1h    <<<gw,   b256, 0, stream>>>(bufB, gW2, s0, n);
  k_agg1_final <<<gw,   b256, 0, stream>>>(row, packed, s0, dinv, gb2, gWl, gbl, xsol, x, (float*)d_out, n);
}

// Round 8
// 625.301 us; speedup vs baseline: 1.3282x; 1.3195x over previous
//
#include <hip/hip_runtime.h>
#include <hip/hip_fp16.h>
#include <math.h>

#define NN 50000
#define NE 1600000
#define NBK 196          // buckets of 256 dst-nodes: cdiv(50000,256)
#define EPB 4096         // edges per block in bucket kernels

typedef unsigned int u32;
typedef _Float16 f16x8 __attribute__((ext_vector_type(8)));
typedef float f32x4 __attribute__((ext_vector_type(4)));

static inline int cdiv(int a, int b){ return (a + b - 1) / b; }

// ---------------- CSR build ----------------

__global__ void k_bcount(const int* __restrict__ dst, int* __restrict__ bcnt, int e){
  __shared__ int h[NBK];
  int t = threadIdx.x;
  for (int b = t; b < NBK; b += 256) h[b] = 0;
  __syncthreads();
  int beg = blockIdx.x*EPB, end = min(beg + EPB, e);
  for (int i = beg + t; i < end; i += 256) atomicAdd(&h[dst[i] >> 8], 1);
  __syncthreads();
  for (int b = t; b < NBK; b += 256) if (h[b]) atomicAdd(&bcnt[b], h[b]);
}

// single block: exclusive scan of bucket counts -> boff[0..NBK]; init bcur; row[n]=e
__global__ void k_scan_bcnt(const int* __restrict__ bcnt, int* __restrict__ boff,
                            int* __restrict__ bcur, int* __restrict__ row){
  __shared__ int sh[256];
  int t = threadIdx.x;
  int v = (t < NBK) ? bcnt[t] : 0;
  sh[t] = v; __syncthreads();
  for (int o = 1; o < 256; o <<= 1){
    int u = (t >= o) ? sh[t-o] : 0;
    __syncthreads();
    sh[t] += u;
    __syncthreads();
  }
  int ex = sh[t] - v;
  if (t <= NBK) boff[t] = ex;
  if (t <  NBK) bcur[t] = ex;
  if (t == 0)   row[NN] = NE;
}

// phase A: bin edges by dst>>8; pack dlow into src high bits (src < 65536)
__global__ void k_bucket(const int* __restrict__ src, const int* __restrict__ dst,
                         const float* __restrict__ ew, int* __restrict__ bcur,
                         int2* __restrict__ seL, int e){
  __shared__ int h[NBK], base[NBK], cur[NBK];
  int t = threadIdx.x;
  for (int b = t; b < NBK; b += 256){ h[b] = 0; cur[b] = 0; }
  __syncthreads();
  int beg = blockIdx.x*EPB, end = min(beg + EPB, e);
  for (int i = beg + t; i < end; i += 256) atomicAdd(&h[dst[i] >> 8], 1);
  __syncthreads();
  for (int b = t; b < NBK; b += 256)
    if (h[b] > 0) base[b] = atomicAdd(&bcur[b], h[b]);
  __syncthreads();
  for (int i = beg + t; i < end; i += 256){
    int d = dst[i], b = d >> 8;
    int pos = base[b] + atomicAdd(&cur[b], 1);
    seL[pos] = make_int2(((d & 255) << 16) | src[i], __float_as_int(ew[i]));
  }
}

// phase B: one block per bucket; per-node hist+scan+scatter+deg in LDS.
// packed entry: lo16 = src, hi16 = fp16 edge weight (later overwritten by norm).
__global__ void k_csr_bucket(const int* __restrict__ boff, const int2* __restrict__ seL,
                             int* __restrict__ row, u32* __restrict__ packed,
                             float* __restrict__ dinv, int n){
  __shared__ int hist[256], sh[256], cur[256];
  __shared__ float wsum[256];
  int b = blockIdx.x, t = threadIdx.x;
  int ebeg = boff[b], eend = boff[b+1];
  hist[t] = 0; wsum[t] = 0.f;
  __syncthreads();
  for (int i = ebeg + t; i < eend; i += 256)
    atomicAdd(&hist[seL[i].x >> 16], 1);
  __syncthreads();
  int v = hist[t];
  sh[t] = v; __syncthreads();
  for (int o = 1; o < 256; o <<= 1){
    int u = (t >= o) ? sh[t-o] : 0;
    __syncthreads();
    sh[t] += u;
    __syncthreads();
  }
  int rowv = ebeg + sh[t] - v;
  int node = b*256 + t;
  if (node < n) row[node] = rowv;
  cur[t] = rowv;
  __syncthreads();
  for (int i = ebeg + t; i < eend; i += 256){
    int2 u = seL[i];
    int d = u.x >> 16;
    int pos = atomicAdd(&cur[d], 1);
    float w = __int_as_float(u.y);
    packed[pos] = (u32)(u.x & 0xFFFF) |
                  ((u32)__half_as_ushort(__float2half(w)) << 16);
    atomicAdd(&wsum[d], w);
  }
  __syncthreads();
  if (node < n) dinv[node] = rsqrtf(1.f + wsum[t]);   // deg >= 1 (self-loop)
}

// one wave per node: hi16 of packed := fp16( ew * dinv[src] * dinv[node] )
__global__ void k_nrm(const int* __restrict__ row, u32* __restrict__ packed,
                      const float* __restrict__ dinv, int n){
  int tid = blockIdx.x*256 + threadIdx.x;
  int node = tid >> 6, lane = tid & 63;
  if (node >= n) return;
  float di = dinv[node];
  int beg = row[node], end = row[node+1];
  for (int p = beg + lane; p < end; p += 64){
    u32 v = packed[p];
    int s = v & 0xFFFF;
    float w = __half2float(__ushort_as_half((unsigned short)(v >> 16)));
    w *= di * dinv[s];
    packed[p] = (v & 0xFFFFu) | ((u32)__half_as_ushort(__float2half(w)) << 16);
  }
}

// ---------------- dense transforms ----------------

// fp32 input [n,FIN] -> fp16 half-split out xwh[2][n][32]; no activation
template<int FIN>
__global__ __launch_bounds__(256, 4)
void k_xform64f(const float* __restrict__ in, const float* __restrict__ W,
                __half* __restrict__ out, int n){
  int j = threadIdx.x & 63;
  int wid = (blockIdx.x*256 + threadIdx.x) >> 6;
  int nw = gridDim.x * 4;
  float wreg[FIN];
  #pragma unroll
  for (int k = 0; k < FIN; ++k) wreg[k] = W[k*64 + j];   // coalesced, once per wave
  size_t outoff = (size_t)(j >> 5)*(size_t)n*32 + (j & 31);
  for (int node = wid; node < n; node += nw){
    const float* r = in + (size_t)node*FIN;
    float acc = 0.f;
    #pragma unroll
    for (int k = 0; k < FIN; ++k) acc = fmaf(r[k], wreg[k], acc);
    out[outoff + (size_t)node*32] = __float2half(acc);
  }
}

// MFMA transform: fp16 in [n,64] -> (relu) -> @W[64,64](fp32, cast fp16) ->
// fp16 half-split out xwh[2][n][32]. One wave = 16-node x 64-feature tile,
// 8x mfma_f32_16x16x32_f16. W held in 8 NAMED B-fragments (no indexable
// array -> no scratch alloca -> no spill, unlike r6/r7's wreg[64]).
// Layouts (HW-verified): A[m=lane&15][k=quad*8+j]; B[k=quad*8+j][col=lane&15];
// C/D: col=lane&15, row=quad*4+reg.
template<bool RELU>
__global__ __attribute__((amdgpu_waves_per_eu(2, 4)))
void k_xform64_mfma(const __half* __restrict__ in, const float* __restrict__ W,
                    __half* __restrict__ out, int n){
  int lane = threadIdx.x & 63;
  int m = lane & 15, q = lane >> 4;
  int wid = (blockIdx.x*256 + threadIdx.x) >> 6;
  int nw = gridDim.x * 4;

  auto ldB = [&](int kk, int ct){
    f16x8 r;
    #pragma unroll
    for (int j = 0; j < 8; ++j)
      r[j] = (_Float16)W[(kk*32 + q*8 + j)*64 + ct*16 + m];
    return r;
  };
  f16x8 b00 = ldB(0,0), b01 = ldB(0,1), b02 = ldB(0,2), b03 = ldB(0,3);
  f16x8 b10 = ldB(1,0), b11 = ldB(1,1), b12 = ldB(1,2), b13 = ldB(1,3);

  int ntiles = n >> 4;                         // 50000 = 16*3125 exactly
  for (int tile = wid; tile < ntiles; tile += nw){
    int base = tile << 4;
    const f16x8* arow = (const f16x8*)(in + (size_t)(base + m)*64);
    f16x8 a0 = arow[q];                        // k = q*8 + j        (K-step 0)
    f16x8 a1 = arow[4 + q];                    // k = 32 + q*8 + j   (K-step 1)
    if (RELU){
      #pragma unroll
      for (int i = 0; i < 8; ++i){
        a0[i] = a0[i] > (_Float16)0 ? a0[i] : (_Float16)0;
        a1[i] = a1[i] > (_Float16)0 ? a1[i] : (_Float16)0;
      }
    }
    f32x4 c0 = {0,0,0,0}, c1 = {0,0,0,0}, c2 = {0,0,0,0}, c3 = {0,0,0,0};
    c0 = __builtin_amdgcn_mfma_f32_16x16x32_f16(a0, b00, c0, 0, 0, 0);
    c0 = __builtin_amdgcn_mfma_f32_16x16x32_f16(a1, b10, c0, 0, 0, 0);
    c1 = __builtin_amdgcn_mfma_f32_16x16x32_f16(a0, b01, c1, 0, 0, 0);
    c1 = __builtin_amdgcn_mfma_f32_16x16x32_f16(a1, b11, c1, 0, 0, 0);
    c2 = __builtin_amdgcn_mfma_f32_16x16x32_f16(a0, b02, c2, 0, 0, 0);
    c2 = __builtin_amdgcn_mfma_f32_16x16x32_f16(a1, b12, c2, 0, 0, 0);
    c3 = __builtin_amdgcn_mfma_f32_16x16x32_f16(a0, b03, c3, 0, 0, 0);
    c3 = __builtin_amdgcn_mfma_f32_16x16x32_f16(a1, b13, c3, 0, 0, 0);

    auto st = [&](const f32x4& c, int ct){
      int ft = ct*16 + m;                      // feature = col
      __half* op = out + (size_t)(ft >> 5)*(size_t)n*32 + (ft & 31);
      #pragma unroll
      for (int r = 0; r < 4; ++r)              // node = row = base + q*4 + r
        op[(size_t)(base + q*4 + r)*32] = __float2half(c[r]);
    };
    st(c0, 0); st(c1, 1); st(c2, 2); st(c3, 3);
  }
}

// fp16 input [n,64] -> relu -> @W[64,1] -> fp32 out[n]; wave per node, lane-parallel
__global__ void k_xform1h(const __half* __restrict__ in, const float* __restrict__ W,
                          float* __restrict__ out, int n){
  int tid = blockIdx.x*256 + threadIdx.x;
  int node = tid >> 6, lane = tid & 63;
  if (node >= n) return;
  float w = W[lane];
  float v = fmaxf(__half2float(in[(size_t)node*64 + lane]), 0.f) * w;
  for (int o = 32; o > 0; o >>= 1) v += __shfl_xor(v, o, 64);
  if (lane == 0) out[node] = v;
}

// ---------------- CSR aggregation: feature-half passes in one launch ----------------

// one wave per node per half; lanes 0-31 even edge, 32-63 odd edge.
// metadata: one u32/lane per 64 edges; gather working set 3.2MB < 4MiB L2.
__global__ void k_agg64h(const int* __restrict__ row, const u32* __restrict__ packed,
                         const __half* __restrict__ xw, const float* __restrict__ dinv,
                         const float* __restrict__ b, __half* __restrict__ out,
                         int n, int gw){
  int blk = blockIdx.x;
  int pass = (blk >= gw) ? 1 : 0;
  if (pass) blk -= gw;
  int tid = blk*256 + threadIdx.x;
  int node = tid >> 6, lane = tid & 63;
  if (node >= n) return;
  int f = lane & 31, ep = lane >> 5;
  const __half* xh = xw + (size_t)pass*(size_t)n*32;
  float acc = 0.f;
  int p = row[node], end = row[node+1];
  for (; p + 64 <= end; p += 64){
    u32 myv = __builtin_nontemporal_load(&packed[p + lane]);   // 64 edges
    #pragma unroll
    for (int t = 0; t < 32; ++t){
      u32 v0 = __builtin_amdgcn_readlane(myv, 2*t);
      u32 v1 = __builtin_amdgcn_readlane(myv, 2*t + 1);
      u32 v = ep ? v1 : v0;
      int s = v & 0xFFFF;
      float w = __half2float(__ushort_as_half((unsigned short)(v >> 16)));
      acc = fmaf(w, __half2float(xh[s*32 + f]), acc);
    }
  }
  int rem = end - p;
  if (rem > 0){
    u32 myv = (lane < rem) ? packed[p + lane] : 0u;   // pad edges: w=0 -> harmless
    int it = (rem + 1) >> 1;
    for (int t = 0; t < it; ++t){
      u32 v0 = __builtin_amdgcn_readlane(myv, 2*t);
      u32 v1 = __builtin_amdgcn_readlane(myv, 2*t + 1);
      u32 v = ep ? v1 : v0;
      int s = v & 0xFFFF;
      float w = __half2float(__ushort_as_half((unsigned short)(v >> 16)));
      acc = fmaf(w, __half2float(xh[s*32 + f]), acc);
    }
  }
  acc += __shfl_xor(acc, 32, 64);                    // combine even/odd partials
  if (ep == 0){
    float di = dinv[node];
    float tot = acc + __half2float(xh[(size_t)node*32 + f])*(di*di) + b[pass*32 + f];
    out[(size_t)node*64 + pass*32 + f] = __float2half(tot);
  }
}

// scalar agg (wave per node) + Linear(1,1) + build xin = cat(x, xsol)
__global__ void k_agg1_xsol(const int* __restrict__ row, const u32* __restrict__ packed,
                            const float* __restrict__ s0, const float* __restrict__ dinv,
                            const float* __restrict__ b, const float* __restrict__ Wl,
                            const float* __restrict__ bl, const float* __restrict__ x,
                            float* __restrict__ xsol, float* __restrict__ xin, int n){
  int tid = blockIdx.x*256 + threadIdx.x;
  int node = tid >> 6, lane = tid & 63;
  if (node >= n) return;
  int beg = row[node], end = row[node+1];
  float acc = 0.f;
  for (int p = beg + lane; p < end; p += 64){
    u32 v = packed[p];
    float w = __half2float(__ushort_as_half((unsigned short)(v >> 16)));
    acc = fmaf(w, s0[v & 0xFFFF], acc);
  }
  for (int o = 32; o > 0; o >>= 1) acc += __shfl_xor(acc, o, 64);
  if (lane == 0){
    float di = dinv[node];
    float v = s0[node]*(di*di) + b[0] + acc;
    v = v*Wl[0] + bl[0];
    xsol[node] = v;
    float4 xv = ((const float4*)x)[node];
    xin[node*5+0] = xv.x;
    xin[node*5+1] = xv.y;
    xin[node*5+2] = xv.z;
    xin[node*5+3] = xv.w;
    xin[node*5+4] = v;
  }
}

// scalar agg + Linear(1,1) + sigmoid + gated residual combine
__global__ void k_agg1_final(const int* __restrict__ row, const u32* __restrict__ packed,
                             const float* __restrict__ s0, const float* __restrict__ dinv,
                             const float* __restrict__ b, const float* __restrict__ Wl,
                             const float* __restrict__ bl, const float* __restrict__ xsol,
                             const float* __restrict__ x, float* __restrict__ out, int n){
  int tid = blockIdx.x*256 + threadIdx.x;
  int node = tid >> 6, lane = tid & 63;
  if (node >= n) return;
  int beg = row[node], end = row[node+1];
  float acc = 0.f;
  for (int p = beg + lane; p < end; p += 64){
    u32 v = packed[p];
    float w = __half2float(__ushort_as_half((unsigned short)(v >> 16)));
    acc = fmaf(w, s0[v & 0xFFFF], acc);
  }
  for (int o = 32; o > 0; o >>= 1) acc += __shfl_xor(acc, o, 64);
  if (lane == 0){
    float di = dinv[node];
    float g = s0[node]*(di*di) + b[0] + acc;
    g = g*Wl[0] + bl[0];
    float gamma = 1.f / (1.f + expf(-g));
    float xl = x[node*4+3];
    out[node]     = xl + gamma*(xsol[node] - xl);
    out[n + node] = gamma;
  }
}

// ---------------- launch ----------------

extern "C" void kernel_launch(void* const* d_in, const int* in_sizes, int n_in,
                              void* d_out, int out_size, void* d_ws, size_t ws_size,
                              hipStream_t stream){
  const float* x   = (const float*)d_in[0];
  const int*   ei  = (const int*)d_in[1];
  const float* ew  = (const float*)d_in[2];
  const float* oW0 = (const float*)d_in[3];
  const float* ob0 = (const float*)d_in[4];
  const float* oW1 = (const float*)d_in[5];
  const float* ob1 = (const float*)d_in[6];
  const float* oW2 = (const float*)d_in[7];
  const float* ob2 = (const float*)d_in[8];
  const float* oWl = (const float*)d_in[9];
  const float* obl = (const float*)d_in[10];
  const float* gW0 = (const float*)d_in[11];
  const float* gb0 = (const float*)d_in[12];
  const float* gW1 = (const float*)d_in[13];
  const float* gb1 = (const float*)d_in[14];
  const float* gW2 = (const float*)d_in[15];
  const float* gb2 = (const float*)d_in[16];
  const float* gWl = (const float*)d_in[17];
  const float* gbl = (const float*)d_in[18];

  const int n = NN, e = NE;
  const int* src = ei;
  const int* dst = ei + e;

  // workspace layout (8B-aligned blocks first)
  char* wsb = (char*)d_ws;
  int2*  seL    = (int2*)wsb;      wsb += (size_t)e*sizeof(int2);      // 12.8 MB
  u32*   packed = (u32*)wsb;       wsb += (size_t)e*4;                 // 6.4 MB
  __half* bufA  = (__half*)wsb;    wsb += (size_t)n*64*2;              // 6.4 MB (xwh[2][n][32])
  __half* bufB  = (__half*)wsb;    wsb += (size_t)n*64*2;              // 6.4 MB ([n][64])
  int*   row    = (int*)wsb;       wsb += (size_t)(n+1)*4;
  int*   bcnt   = (int*)wsb;       wsb += 256*4;
  int*   boff   = (int*)wsb;       wsb += 256*4;
  int*   bcur   = (int*)wsb;       wsb += 256*4;
  float* dinv   = (float*)wsb;     wsb += (size_t)n*4;
  float* s0     = (float*)wsb;     wsb += (size_t)n*4;
  float* xsol   = (float*)wsb;     wsb += (size_t)n*4;
  float* xin    = (float*)wsb;     wsb += (size_t)n*5*4;

  dim3 b256(256);
  int gn = cdiv(n, 256);           // 196
  int gw = cdiv(n*64, 256);        // 12500 (wave-per-node kernels)
  int gb = cdiv(e, EPB);           // 391
  int gx = 512;                    // multi-node-wave transform grids
  int gxm = 512;                   // MFMA transform grid (2048 waves, ~1.5 tiles each)

  // ---- CSR build + normalization (shared by all 6 convs) ----
  hipMemsetAsync(bcnt, 0, 256*4, stream);
  k_bcount    <<<gb,  b256, 0, stream>>>(dst, bcnt, e);
  k_scan_bcnt <<<1,   b256, 0, stream>>>(bcnt, boff, bcur, row);
  k_bucket    <<<gb,  b256, 0, stream>>>(src, dst, ew, bcur, seL, e);
  k_csr_bucket<<<NBK, b256, 0, stream>>>(boff, seL, row, packed, dinv, n);
  k_nrm       <<<gw,  b256, 0, stream>>>(row, packed, dinv, n);

  // ---- optim tower: 4 -> 64 -> 64 -> 1, Linear(1,1) ----
  k_xform64f<4>      <<<gx,   b256, 0, stream>>>(x, oW0, bufA, n);
  k_agg64h           <<<2*gw, b256, 0, stream>>>(row, packed, bufA, dinv, ob0, bufB, n, gw);
  k_xform64_mfma<true><<<gxm, b256, 0, stream>>>(bufB, oW1, bufA, n);
  k_agg64h           <<<2*gw, b256, 0, stream>>>(row, packed, bufA, dinv, ob1, bufB, n, gw);
  k_xform1h          <<<gw,   b256, 0, stream>>>(bufB, oW2, s0, n);
  k_agg1_xsol        <<<gw,   b256, 0, stream>>>(row, packed, s0, dinv, ob2, oWl, obl, x, xsol, xin, n);

  // ---- gamma tower: 5 -> 64 -> 64 -> 1, Linear(1,1), sigmoid ----
  k_xform64f<5>      <<<gx,   b256, 0, stream>>>(xin, gW0, bufA, n);
  k_agg64h           <<<2*gw, b256, 0, stream>>>(row, packed, bufA, dinv, gb0, bufB, n, gw);
  k_xform64_mfma<true><<<gxm, b256, 0, stream>>>(bufB, gW1, bufA, n);
  k_agg64h           <<<2*gw, b256, 0, stream>>>(row, packed, bufA, dinv, gb1, bufB, n, gw);
  k_xform1h          <<<gw,   b256, 0, stream>>>(bufB, gW2, s0, n);
  k_agg1_final       <<<gw,   b256, 0, stream>>>(row, packed, s0, dinv, gb2, gWl, gbl, xsol, x, (float*)d_out, n);
}

// Round 9
// 493.293 us; speedup vs baseline: 1.6837x; 1.2676x over previous
//
#include <hip/hip_runtime.h>
#include <hip/hip_fp16.h>
#include <math.h>

#define NN 50000
#define NE 1600000
#define NBK 196          // buckets of 256 dst-nodes: cdiv(50000,256)
#define EPB 4096         // edges per block in bucket kernels

typedef unsigned int u32;
typedef _Float16 f16x8 __attribute__((ext_vector_type(8)));
typedef float f32x4 __attribute__((ext_vector_type(4)));

static inline int cdiv(int a, int b){ return (a + b - 1) / b; }

// ---------------- CSR build ----------------

__global__ void k_bcount(const int* __restrict__ dst, int* __restrict__ bcnt, int e){
  __shared__ int h[NBK];
  int t = threadIdx.x;
  for (int b = t; b < NBK; b += 256) h[b] = 0;
  __syncthreads();
  int beg = blockIdx.x*EPB, end = min(beg + EPB, e);
  for (int i = beg + t; i < end; i += 256) atomicAdd(&h[dst[i] >> 8], 1);
  __syncthreads();
  for (int b = t; b < NBK; b += 256) if (h[b]) atomicAdd(&bcnt[b], h[b]);
}

// single block: exclusive scan of bucket counts -> boff[0..NBK]; init bcur; row[n]=e
__global__ void k_scan_bcnt(const int* __restrict__ bcnt, int* __restrict__ boff,
                            int* __restrict__ bcur, int* __restrict__ row){
  __shared__ int sh[256];
  int t = threadIdx.x;
  int v = (t < NBK) ? bcnt[t] : 0;
  sh[t] = v; __syncthreads();
  for (int o = 1; o < 256; o <<= 1){
    int u = (t >= o) ? sh[t-o] : 0;
    __syncthreads();
    sh[t] += u;
    __syncthreads();
  }
  int ex = sh[t] - v;
  if (t <= NBK) boff[t] = ex;
  if (t <  NBK) bcur[t] = ex;
  if (t == 0)   row[NN] = NE;
}

// phase A: bin edges by dst>>8; pack dlow into src high bits (src < 65536)
__global__ void k_bucket(const int* __restrict__ src, const int* __restrict__ dst,
                         const float* __restrict__ ew, int* __restrict__ bcur,
                         int2* __restrict__ seL, int e){
  __shared__ int h[NBK], base[NBK], cur[NBK];
  int t = threadIdx.x;
  for (int b = t; b < NBK; b += 256){ h[b] = 0; cur[b] = 0; }
  __syncthreads();
  int beg = blockIdx.x*EPB, end = min(beg + EPB, e);
  for (int i = beg + t; i < end; i += 256) atomicAdd(&h[dst[i] >> 8], 1);
  __syncthreads();
  for (int b = t; b < NBK; b += 256)
    if (h[b] > 0) base[b] = atomicAdd(&bcur[b], h[b]);
  __syncthreads();
  for (int i = beg + t; i < end; i += 256){
    int d = dst[i], b = d >> 8;
    int pos = base[b] + atomicAdd(&cur[b], 1);
    seL[pos] = make_int2(((d & 255) << 16) | src[i], __float_as_int(ew[i]));
  }
}

// phase B: one block per bucket; per-node hist+scan+scatter+deg in LDS.
// packed entry: lo16 = src, hi16 = fp16 edge weight (later overwritten by norm).
__global__ void k_csr_bucket(const int* __restrict__ boff, const int2* __restrict__ seL,
                             int* __restrict__ row, u32* __restrict__ packed,
                             float* __restrict__ dinv, int n){
  __shared__ int hist[256], sh[256], cur[256];
  __shared__ float wsum[256];
  int b = blockIdx.x, t = threadIdx.x;
  int ebeg = boff[b], eend = boff[b+1];
  hist[t] = 0; wsum[t] = 0.f;
  __syncthreads();
  for (int i = ebeg + t; i < eend; i += 256)
    atomicAdd(&hist[seL[i].x >> 16], 1);
  __syncthreads();
  int v = hist[t];
  sh[t] = v; __syncthreads();
  for (int o = 1; o < 256; o <<= 1){
    int u = (t >= o) ? sh[t-o] : 0;
    __syncthreads();
    sh[t] += u;
    __syncthreads();
  }
  int rowv = ebeg + sh[t] - v;
  int node = b*256 + t;
  if (node < n) row[node] = rowv;
  cur[t] = rowv;
  __syncthreads();
  for (int i = ebeg + t; i < eend; i += 256){
    int2 u = seL[i];
    int d = u.x >> 16;
    int pos = atomicAdd(&cur[d], 1);
    float w = __int_as_float(u.y);
    packed[pos] = (u32)(u.x & 0xFFFF) |
                  ((u32)__half_as_ushort(__float2half(w)) << 16);
    atomicAdd(&wsum[d], w);
  }
  __syncthreads();
  if (node < n) dinv[node] = rsqrtf(1.f + wsum[t]);   // deg >= 1 (self-loop)
}

// one wave per node: hi16 of packed := fp16( ew * dinv[src] * dinv[node] )
__global__ void k_nrm(const int* __restrict__ row, u32* __restrict__ packed,
                      const float* __restrict__ dinv, int n){
  int tid = blockIdx.x*256 + threadIdx.x;
  int node = tid >> 6, lane = tid & 63;
  if (node >= n) return;
  float di = dinv[node];
  int beg = row[node], end = row[node+1];
  for (int p = beg + lane; p < end; p += 64){
    u32 v = packed[p];
    int s = v & 0xFFFF;
    float w = __half2float(__ushort_as_half((unsigned short)(v >> 16)));
    w *= di * dinv[s];
    packed[p] = (v & 0xFFFFu) | ((u32)__half_as_ushort(__float2half(w)) << 16);
  }
}

// ---------------- dense transforms ----------------

// fp32 input [n,FIN] -> fp16 out [n][64]; no activation
template<int FIN>
__global__ __launch_bounds__(256, 4)
void k_xform64f(const float* __restrict__ in, const float* __restrict__ W,
                __half* __restrict__ out, int n){
  int j = threadIdx.x & 63;
  int wid = (blockIdx.x*256 + threadIdx.x) >> 6;
  int nw = gridDim.x * 4;
  float wreg[FIN];
  #pragma unroll
  for (int k = 0; k < FIN; ++k) wreg[k] = W[k*64 + j];   // coalesced, once per wave
  for (int node = wid; node < n; node += nw){
    const float* r = in + (size_t)node*FIN;
    float acc = 0.f;
    #pragma unroll
    for (int k = 0; k < FIN; ++k) acc = fmaf(r[k], wreg[k], acc);
    out[(size_t)node*64 + j] = __float2half(acc);
  }
}

// MFMA transform: fp16 in [n,64] -> relu -> @W[64,64](fp32, cast fp16) ->
// fp16 out [n][64]. One wave = 16-node x 64-feature tile,
// 8x mfma_f32_16x16x32_f16. W in 8 NAMED B-fragments (no indexable array ->
// no scratch spill). Layouts (HW-verified): A[m=lane&15][k=quad*8+j];
// B[k=quad*8+j][col=lane&15]; C/D: col=lane&15, row=quad*4+reg.
template<bool RELU>
__global__ __attribute__((amdgpu_waves_per_eu(2, 4)))
void k_xform64_mfma(const __half* __restrict__ in, const float* __restrict__ W,
                    __half* __restrict__ out, int n){
  int lane = threadIdx.x & 63;
  int m = lane & 15, q = lane >> 4;
  int wid = (blockIdx.x*256 + threadIdx.x) >> 6;
  int nw = gridDim.x * 4;

  auto ldB = [&](int kk, int ct){
    f16x8 r;
    #pragma unroll
    for (int j = 0; j < 8; ++j)
      r[j] = (_Float16)W[(kk*32 + q*8 + j)*64 + ct*16 + m];
    return r;
  };
  f16x8 b00 = ldB(0,0), b01 = ldB(0,1), b02 = ldB(0,2), b03 = ldB(0,3);
  f16x8 b10 = ldB(1,0), b11 = ldB(1,1), b12 = ldB(1,2), b13 = ldB(1,3);

  int ntiles = n >> 4;                         // 50000 = 16*3125 exactly
  for (int tile = wid; tile < ntiles; tile += nw){
    int base = tile << 4;
    const f16x8* arow = (const f16x8*)(in + (size_t)(base + m)*64);
    f16x8 a0 = arow[q];                        // k = q*8 + j        (K-step 0)
    f16x8 a1 = arow[4 + q];                    // k = 32 + q*8 + j   (K-step 1)
    if (RELU){
      #pragma unroll
      for (int i = 0; i < 8; ++i){
        a0[i] = a0[i] > (_Float16)0 ? a0[i] : (_Float16)0;
        a1[i] = a1[i] > (_Float16)0 ? a1[i] : (_Float16)0;
      }
    }
    f32x4 c0 = {0,0,0,0}, c1 = {0,0,0,0}, c2 = {0,0,0,0}, c3 = {0,0,0,0};
    c0 = __builtin_amdgcn_mfma_f32_16x16x32_f16(a0, b00, c0, 0, 0, 0);
    c0 = __builtin_amdgcn_mfma_f32_16x16x32_f16(a1, b10, c0, 0, 0, 0);
    c1 = __builtin_amdgcn_mfma_f32_16x16x32_f16(a0, b01, c1, 0, 0, 0);
    c1 = __builtin_amdgcn_mfma_f32_16x16x32_f16(a1, b11, c1, 0, 0, 0);
    c2 = __builtin_amdgcn_mfma_f32_16x16x32_f16(a0, b02, c2, 0, 0, 0);
    c2 = __builtin_amdgcn_mfma_f32_16x16x32_f16(a1, b12, c2, 0, 0, 0);
    c3 = __builtin_amdgcn_mfma_f32_16x16x32_f16(a0, b03, c3, 0, 0, 0);
    c3 = __builtin_amdgcn_mfma_f32_16x16x32_f16(a1, b13, c3, 0, 0, 0);

    auto st = [&](const f32x4& c, int ct){
      int ft = ct*16 + m;                      // feature = col
      #pragma unroll
      for (int r = 0; r < 4; ++r)              // node = row = base + q*4 + r
        out[(size_t)(base + q*4 + r)*64 + ft] = __float2half(c[r]);
    };
    st(c0, 0); st(c1, 1); st(c2, 2); st(c3, 3);
  }
}

// fp16 input [n,64] -> relu -> @W[64,1] -> fp32 out[n]; wave per node, lane-parallel
__global__ void k_xform1h(const __half* __restrict__ in, const float* __restrict__ W,
                          float* __restrict__ out, int n){
  int tid = blockIdx.x*256 + threadIdx.x;
  int node = tid >> 6, lane = tid & 63;
  if (node >= n) return;
  float w = W[lane];
  float v = fmaxf(__half2float(in[(size_t)node*64 + lane]), 0.f) * w;
  for (int o = 32; o > 0; o >>= 1) v += __shfl_xor(v, o, 64);
  if (lane == 0) out[node] = v;
}

// ---------------- CSR aggregation: single pass, half2 gathers ----------------

// one wave per node; lane = (edge parity ep, feature-pair f2). Per 2 edges:
// one metadata broadcast + ONE 128B half2 gather covering all 64 features.
__global__ void k_agg64(const int* __restrict__ row, const u32* __restrict__ packed,
                        const __half* __restrict__ xw, const float* __restrict__ dinv,
                        const float* __restrict__ b, __half* __restrict__ out, int n){
  int tid = blockIdx.x*256 + threadIdx.x;
  int node = tid >> 6, lane = tid & 63;
  if (node >= n) return;
  int f2 = lane & 31, ep = lane >> 5;
  const __half2* xw2 = (const __half2*)xw;
  float ax = 0.f, ay = 0.f;
  int p = row[node], end = row[node+1];
  for (; p + 64 <= end; p += 64){
    u32 myv = __builtin_nontemporal_load(&packed[p + lane]);   // 64 edges
    #pragma unroll
    for (int t = 0; t < 32; ++t){
      u32 v0 = __builtin_amdgcn_readlane(myv, 2*t);
      u32 v1 = __builtin_amdgcn_readlane(myv, 2*t + 1);
      u32 v = ep ? v1 : v0;
      int s = v & 0xFFFF;
      float w = __half2float(__ushort_as_half((unsigned short)(v >> 16)));
      float2 xf = __half22float2(xw2[s*32 + f2]);
      ax = fmaf(w, xf.x, ax);
      ay = fmaf(w, xf.y, ay);
    }
  }
  int rem = end - p;
  if (rem > 0){
    u32 myv = (lane < rem) ? packed[p + lane] : 0u;   // pad edges: w=0 -> harmless
    int it = (rem + 1) >> 1;
    for (int t = 0; t < it; ++t){
      u32 v0 = __builtin_amdgcn_readlane(myv, 2*t);
      u32 v1 = __builtin_amdgcn_readlane(myv, 2*t + 1);
      u32 v = ep ? v1 : v0;
      int s = v & 0xFFFF;
      float w = __half2float(__ushort_as_half((unsigned short)(v >> 16)));
      float2 xf = __half22float2(xw2[s*32 + f2]);
      ax = fmaf(w, xf.x, ax);
      ay = fmaf(w, xf.y, ay);
    }
  }
  ax += __shfl_xor(ax, 32, 64);                 // combine even/odd edge partials
  ay += __shfl_xor(ay, 32, 64);
  if (ep == 0){
    float di = dinv[node];
    float2 sf = __half22float2(xw2[(size_t)node*32 + f2]);
    float ox = ax + sf.x*(di*di) + b[2*f2];
    float oy = ay + sf.y*(di*di) + b[2*f2 + 1];
    ((__half2*)out)[(size_t)node*32 + f2] = __floats2half2_rn(ox, oy);
  }
}

// scalar agg (wave per node) + Linear(1,1) + build xin = cat(x, xsol)
__global__ void k_agg1_xsol(const int* __restrict__ row, const u32* __restrict__ packed,
                            const float* __restrict__ s0, const float* __restrict__ dinv,
                            const float* __restrict__ b, const float* __restrict__ Wl,
                            const float* __restrict__ bl, const float* __restrict__ x,
                            float* __restrict__ xsol, float* __restrict__ xin, int n){
  int tid = blockIdx.x*256 + threadIdx.x;
  int node = tid >> 6, lane = tid & 63;
  if (node >= n) return;
  int beg = row[node], end = row[node+1];
  float acc = 0.f;
  for (int p = beg + lane; p < end; p += 64){
    u32 v = packed[p];
    float w = __half2float(__ushort_as_half((unsigned short)(v >> 16)));
    acc = fmaf(w, s0[v & 0xFFFF], acc);
  }
  for (int o = 32; o > 0; o >>= 1) acc += __shfl_xor(acc, o, 64);
  if (lane == 0){
    float di = dinv[node];
    float v = s0[node]*(di*di) + b[0] + acc;
    v = v*Wl[0] + bl[0];
    xsol[node] = v;
    float4 xv = ((const float4*)x)[node];
    xin[node*5+0] = xv.x;
    xin[node*5+1] = xv.y;
    xin[node*5+2] = xv.z;
    xin[node*5+3] = xv.w;
    xin[node*5+4] = v;
  }
}

// scalar agg + Linear(1,1) + sigmoid + gated residual combine
__global__ void k_agg1_final(const int* __restrict__ row, const u32* __restrict__ packed,
                             const float* __restrict__ s0, const float* __restrict__ dinv,
                             const float* __restrict__ b, const float* __restrict__ Wl,
                             const float* __restrict__ bl, const float* __restrict__ xsol,
                             const float* __restrict__ x, float* __restrict__ out, int n){
  int tid = blockIdx.x*256 + threadIdx.x;
  int node = tid >> 6, lane = tid & 63;
  if (node >= n) return;
  int beg = row[node], end = row[node+1];
  float acc = 0.f;
  for (int p = beg + lane; p < end; p += 64){
    u32 v = packed[p];
    float w = __half2float(__ushort_as_half((unsigned short)(v >> 16)));
    acc = fmaf(w, s0[v & 0xFFFF], acc);
  }
  for (int o = 32; o > 0; o >>= 1) acc += __shfl_xor(acc, o, 64);
  if (lane == 0){
    float di = dinv[node];
    float g = s0[node]*(di*di) + b[0] + acc;
    g = g*Wl[0] + bl[0];
    float gamma = 1.f / (1.f + expf(-g));
    float xl = x[node*4+3];
    out[node]     = xl + gamma*(xsol[node] - xl);
    out[n + node] = gamma;
  }
}

// ---------------- launch ----------------

extern "C" void kernel_launch(void* const* d_in, const int* in_sizes, int n_in,
                              void* d_out, int out_size, void* d_ws, size_t ws_size,
                              hipStream_t stream){
  const float* x   = (const float*)d_in[0];
  const int*   ei  = (const int*)d_in[1];
  const float* ew  = (const float*)d_in[2];
  const float* oW0 = (const float*)d_in[3];
  const float* ob0 = (const float*)d_in[4];
  const float* oW1 = (const float*)d_in[5];
  const float* ob1 = (const float*)d_in[6];
  const float* oW2 = (const float*)d_in[7];
  const float* ob2 = (const float*)d_in[8];
  const float* oWl = (const float*)d_in[9];
  const float* obl = (const float*)d_in[10];
  const float* gW0 = (const float*)d_in[11];
  const float* gb0 = (const float*)d_in[12];
  const float* gW1 = (const float*)d_in[13];
  const float* gb1 = (const float*)d_in[14];
  const float* gW2 = (const float*)d_in[15];
  const float* gb2 = (const float*)d_in[16];
  const float* gWl = (const float*)d_in[17];
  const float* gbl = (const float*)d_in[18];

  const int n = NN, e = NE;
  const int* src = ei;
  const int* dst = ei + e;

  // workspace layout (8B-aligned blocks first)
  char* wsb = (char*)d_ws;
  int2*  seL    = (int2*)wsb;      wsb += (size_t)e*sizeof(int2);      // 12.8 MB
  u32*   packed = (u32*)wsb;       wsb += (size_t)e*4;                 // 6.4 MB
  __half* bufA  = (__half*)wsb;    wsb += (size_t)n*64*2;              // 6.4 MB ([n][64])
  __half* bufB  = (__half*)wsb;    wsb += (size_t)n*64*2;              // 6.4 MB ([n][64])
  int*   row    = (int*)wsb;       wsb += (size_t)(n+1)*4;
  int*   bcnt   = (int*)wsb;       wsb += 256*4;
  int*   boff   = (int*)wsb;       wsb += 256*4;
  int*   bcur   = (int*)wsb;       wsb += 256*4;
  float* dinv   = (float*)wsb;     wsb += (size_t)n*4;
  float* s0     = (float*)wsb;     wsb += (size_t)n*4;
  float* xsol   = (float*)wsb;     wsb += (size_t)n*4;
  float* xin    = (float*)wsb;     wsb += (size_t)n*5*4;

  dim3 b256(256);
  int gn = cdiv(n, 256);           // 196
  int gw = cdiv(n*64, 256);        // 12500 (wave-per-node kernels)
  int gb = cdiv(e, EPB);           // 391
  int gx = 512;                    // multi-node-wave transform grids
  int gxm = 512;                   // MFMA transform grid

  // ---- CSR build + normalization (shared by all 6 convs) ----
  hipMemsetAsync(bcnt, 0, 256*4, stream);
  k_bcount    <<<gb,  b256, 0, stream>>>(dst, bcnt, e);
  k_scan_bcnt <<<1,   b256, 0, stream>>>(bcnt, boff, bcur, row);
  k_bucket    <<<gb,  b256, 0, stream>>>(src, dst, ew, bcur, seL, e);
  k_csr_bucket<<<NBK, b256, 0, stream>>>(boff, seL, row, packed, dinv, n);
  k_nrm       <<<gw,  b256, 0, stream>>>(row, packed, dinv, n);

  // ---- optim tower: 4 -> 64 -> 64 -> 1, Linear(1,1) ----
  k_xform64f<4>      <<<gx,  b256, 0, stream>>>(x, oW0, bufA, n);
  k_agg64            <<<gw,  b256, 0, stream>>>(row, packed, bufA, dinv, ob0, bufB, n);
  k_xform64_mfma<true><<<gxm, b256, 0, stream>>>(bufB, oW1, bufA, n);
  k_agg64            <<<gw,  b256, 0, stream>>>(row, packed, bufA, dinv, ob1, bufB, n);
  k_xform1h          <<<gw,  b256, 0, stream>>>(bufB, oW2, s0, n);
  k_agg1_xsol        <<<gw,  b256, 0, stream>>>(row, packed, s0, dinv, ob2, oWl, obl, x, xsol, xin, n);

  // ---- gamma tower: 5 -> 64 -> 64 -> 1, Linear(1,1), sigmoid ----
  k_xform64f<5>      <<<gx,  b256, 0, stream>>>(xin, gW0, bufA, n);
  k_agg64            <<<gw,  b256, 0, stream>>>(row, packed, bufA, dinv, gb0, bufB, n);
  k_xform64_mfma<true><<<gxm, b256, 0, stream>>>(bufB, gW1, bufA, n);
  k_agg64            <<<gw,  b256, 0, stream>>>(row, packed, bufA, dinv, gb1, bufB, n);
  k_xform1h          <<<gw,  b256, 0, stream>>>(bufB, gW2, s0, n);
  k_agg1_final       <<<gw,  b256, 0, stream>>>(row, packed, s0, dinv, gb2, gWl, gbl, xsol, x, (float*)d_out, n);
}

// Round 10
// 387.234 us; speedup vs baseline: 2.1448x; 1.2739x over previous
//
#include <hip/hip_runtime.h>
#include <hip/hip_fp16.h>
#include <math.h>

#define NN 50000
#define NE 1600000
#define NBK 196          // buckets of 256 dst-nodes: cdiv(50000,256)
#define EPB 4096         // edges per block in bucket kernels

typedef unsigned int u32;
typedef _Float16 f16x8 __attribute__((ext_vector_type(8)));
typedef float f32x4 __attribute__((ext_vector_type(4)));

static inline int cdiv(int a, int b){ return (a + b - 1) / b; }

// ---------------- CSR build ----------------

__global__ void k_bcount(const int* __restrict__ dst, int* __restrict__ bcnt, int e){
  __shared__ int h[NBK];
  int t = threadIdx.x;
  for (int b = t; b < NBK; b += 256) h[b] = 0;
  __syncthreads();
  int beg = blockIdx.x*EPB, end = min(beg + EPB, e);
  for (int i = beg + t; i < end; i += 256) atomicAdd(&h[dst[i] >> 8], 1);
  __syncthreads();
  for (int b = t; b < NBK; b += 256) if (h[b]) atomicAdd(&bcnt[b], h[b]);
}

// single block: exclusive scan of bucket counts -> boff[0..NBK]; init bcur; row[n]=e
__global__ void k_scan_bcnt(const int* __restrict__ bcnt, int* __restrict__ boff,
                            int* __restrict__ bcur, int* __restrict__ row){
  __shared__ int sh[256];
  int t = threadIdx.x;
  int v = (t < NBK) ? bcnt[t] : 0;
  sh[t] = v; __syncthreads();
  for (int o = 1; o < 256; o <<= 1){
    int u = (t >= o) ? sh[t-o] : 0;
    __syncthreads();
    sh[t] += u;
    __syncthreads();
  }
  int ex = sh[t] - v;
  if (t <= NBK) boff[t] = ex;
  if (t <  NBK) bcur[t] = ex;
  if (t == 0)   row[NN] = NE;
}

// phase A: bin edges by dst>>8; pack dlow into src high bits (src < 65536)
__global__ void k_bucket(const int* __restrict__ src, const int* __restrict__ dst,
                         const float* __restrict__ ew, int* __restrict__ bcur,
                         int2* __restrict__ seL, int e){
  __shared__ int h[NBK], base[NBK], cur[NBK];
  int t = threadIdx.x;
  for (int b = t; b < NBK; b += 256){ h[b] = 0; cur[b] = 0; }
  __syncthreads();
  int beg = blockIdx.x*EPB, end = min(beg + EPB, e);
  for (int i = beg + t; i < end; i += 256) atomicAdd(&h[dst[i] >> 8], 1);
  __syncthreads();
  for (int b = t; b < NBK; b += 256)
    if (h[b] > 0) base[b] = atomicAdd(&bcur[b], h[b]);
  __syncthreads();
  for (int i = beg + t; i < end; i += 256){
    int d = dst[i], b = d >> 8;
    int pos = base[b] + atomicAdd(&cur[b], 1);
    seL[pos] = make_int2(((d & 255) << 16) | src[i], __float_as_int(ew[i]));
  }
}

// phase B: one block per bucket; per-node hist+scan+scatter+deg in LDS.
// packed entry: lo16 = src, hi16 = fp16 edge weight (later overwritten by norm).
__global__ void k_csr_bucket(const int* __restrict__ boff, const int2* __restrict__ seL,
                             int* __restrict__ row, u32* __restrict__ packed,
                             float* __restrict__ dinv, int n){
  __shared__ int hist[256], sh[256], cur[256];
  __shared__ float wsum[256];
  int b = blockIdx.x, t = threadIdx.x;
  int ebeg = boff[b], eend = boff[b+1];
  hist[t] = 0; wsum[t] = 0.f;
  __syncthreads();
  for (int i = ebeg + t; i < eend; i += 256)
    atomicAdd(&hist[seL[i].x >> 16], 1);
  __syncthreads();
  int v = hist[t];
  sh[t] = v; __syncthreads();
  for (int o = 1; o < 256; o <<= 1){
    int u = (t >= o) ? sh[t-o] : 0;
    __syncthreads();
    sh[t] += u;
    __syncthreads();
  }
  int rowv = ebeg + sh[t] - v;
  int node = b*256 + t;
  if (node < n) row[node] = rowv;
  cur[t] = rowv;
  __syncthreads();
  for (int i = ebeg + t; i < eend; i += 256){
    int2 u = seL[i];
    int d = u.x >> 16;
    int pos = atomicAdd(&cur[d], 1);
    float w = __int_as_float(u.y);
    packed[pos] = (u32)(u.x & 0xFFFF) |
                  ((u32)__half_as_ushort(__float2half(w)) << 16);
    atomicAdd(&wsum[d], w);
  }
  __syncthreads();
  if (node < n) dinv[node] = rsqrtf(1.f + wsum[t]);   // deg >= 1 (self-loop)
}

// one wave per node: hi16 of packed := fp16( ew * dinv[src] * dinv[node] )
__global__ void k_nrm(const int* __restrict__ row, u32* __restrict__ packed,
                      const float* __restrict__ dinv, int n){
  int tid = blockIdx.x*256 + threadIdx.x;
  int node = tid >> 6, lane = tid & 63;
  if (node >= n) return;
  float di = dinv[node];
  int beg = row[node], end = row[node+1];
  for (int p = beg + lane; p < end; p += 64){
    u32 v = packed[p];
    int s = v & 0xFFFF;
    float w = __half2float(__ushort_as_half((unsigned short)(v >> 16)));
    w *= di * dinv[s];
    packed[p] = (v & 0xFFFFu) | ((u32)__half_as_ushort(__float2half(w)) << 16);
  }
}

// ---------------- dense transforms ----------------

// fp32 input [n,FIN] -> fp16 out [n][64]; no activation
template<int FIN>
__global__ __launch_bounds__(256, 4)
void k_xform64f(const float* __restrict__ in, const float* __restrict__ W,
                __half* __restrict__ out, int n){
  int j = threadIdx.x & 63;
  int wid = (blockIdx.x*256 + threadIdx.x) >> 6;
  int nw = gridDim.x * 4;
  float wreg[FIN];
  #pragma unroll
  for (int k = 0; k < FIN; ++k) wreg[k] = W[k*64 + j];   // coalesced, once per wave
  for (int node = wid; node < n; node += nw){
    const float* r = in + (size_t)node*FIN;
    float acc = 0.f;
    #pragma unroll
    for (int k = 0; k < FIN; ++k) acc = fmaf(r[k], wreg[k], acc);
    out[(size_t)node*64 + j] = __float2half(acc);
  }
}

// MFMA transform: fp16 in [n,64] -> relu -> @W[64,64](fp32, cast fp16) ->
// fp16 out [n][64]. One wave = 16-node x 64-feature tile,
// 8x mfma_f32_16x16x32_f16. W in 8 NAMED B-fragments (no indexable array ->
// no scratch spill). Layouts (HW-verified): A[m=lane&15][k=quad*8+j];
// B[k=quad*8+j][col=lane&15]; C/D: col=lane&15, row=quad*4+reg.
template<bool RELU>
__global__ __attribute__((amdgpu_waves_per_eu(2, 4)))
void k_xform64_mfma(const __half* __restrict__ in, const float* __restrict__ W,
                    __half* __restrict__ out, int n){
  int lane = threadIdx.x & 63;
  int m = lane & 15, q = lane >> 4;
  int wid = (blockIdx.x*256 + threadIdx.x) >> 6;
  int nw = gridDim.x * 4;

  auto ldB = [&](int kk, int ct){
    f16x8 r;
    #pragma unroll
    for (int j = 0; j < 8; ++j)
      r[j] = (_Float16)W[(kk*32 + q*8 + j)*64 + ct*16 + m];
    return r;
  };
  f16x8 b00 = ldB(0,0), b01 = ldB(0,1), b02 = ldB(0,2), b03 = ldB(0,3);
  f16x8 b10 = ldB(1,0), b11 = ldB(1,1), b12 = ldB(1,2), b13 = ldB(1,3);

  int ntiles = n >> 4;                         // 50000 = 16*3125 exactly
  for (int tile = wid; tile < ntiles; tile += nw){
    int base = tile << 4;
    const f16x8* arow = (const f16x8*)(in + (size_t)(base + m)*64);
    f16x8 a0 = arow[q];                        // k = q*8 + j        (K-step 0)
    f16x8 a1 = arow[4 + q];                    // k = 32 + q*8 + j   (K-step 1)
    if (RELU){
      #pragma unroll
      for (int i = 0; i < 8; ++i){
        a0[i] = a0[i] > (_Float16)0 ? a0[i] : (_Float16)0;
        a1[i] = a1[i] > (_Float16)0 ? a1[i] : (_Float16)0;
      }
    }
    f32x4 c0 = {0,0,0,0}, c1 = {0,0,0,0}, c2 = {0,0,0,0}, c3 = {0,0,0,0};
    c0 = __builtin_amdgcn_mfma_f32_16x16x32_f16(a0, b00, c0, 0, 0, 0);
    c0 = __builtin_amdgcn_mfma_f32_16x16x32_f16(a1, b10, c0, 0, 0, 0);
    c1 = __builtin_amdgcn_mfma_f32_16x16x32_f16(a0, b01, c1, 0, 0, 0);
    c1 = __builtin_amdgcn_mfma_f32_16x16x32_f16(a1, b11, c1, 0, 0, 0);
    c2 = __builtin_amdgcn_mfma_f32_16x16x32_f16(a0, b02, c2, 0, 0, 0);
    c2 = __builtin_amdgcn_mfma_f32_16x16x32_f16(a1, b12, c2, 0, 0, 0);
    c3 = __builtin_amdgcn_mfma_f32_16x16x32_f16(a0, b03, c3, 0, 0, 0);
    c3 = __builtin_amdgcn_mfma_f32_16x16x32_f16(a1, b13, c3, 0, 0, 0);

    auto st = [&](const f32x4& c, int ct){
      int ft = ct*16 + m;                      // feature = col
      #pragma unroll
      for (int r = 0; r < 4; ++r)              // node = row = base + q*4 + r
        out[(size_t)(base + q*4 + r)*64 + ft] = __float2half(c[r]);
    };
    st(c0, 0); st(c1, 1); st(c2, 2); st(c3, 3);
  }
}

// fp16 input [n,64] -> relu -> @W[64,1] -> fp32 out[n]; wave per node, lane-parallel
__global__ void k_xform1h(const __half* __restrict__ in, const float* __restrict__ W,
                          float* __restrict__ out, int n){
  int tid = blockIdx.x*256 + threadIdx.x;
  int node = tid >> 6, lane = tid & 63;
  if (node >= n) return;
  float w = W[lane];
  float v = fmaxf(__half2float(in[(size_t)node*64 + lane]), 0.f) * w;
  for (int o = 32; o > 0; o >>= 1) v += __shfl_xor(v, o, 64);
  if (lane == 0) out[node] = v;
}

// ---------------- CSR aggregation: single pass, half2 gathers ----------------
// one wave per node; lane = (edge parity ep, feature-pair f2).
// Poisson(32) in-degree => nearly all nodes have <64 edges: the whole edge
// list is handled by ONE zero-padded, FULLY UNROLLED tail (16+16 iters,
// second block skipped when rem<=32). Straight-line body => ~16 gathers in
// flight per wave (r9's runtime remainder loop kept ~1 in flight => 59us
// HBM-latency chain). Padded slots: s=0,w=0 -> fma adds 0, gather hits one
// hot line. waves_per_eu(4,8): 128-VGPR budget for the in-flight gathers.
__global__ __attribute__((amdgpu_waves_per_eu(4, 8)))
void k_agg64(const int* __restrict__ row, const u32* __restrict__ packed,
             const __half* __restrict__ xw, const float* __restrict__ dinv,
             const float* __restrict__ b, __half* __restrict__ out, int n){
  int tid = blockIdx.x*256 + threadIdx.x;
  int node = tid >> 6, lane = tid & 63;
  if (node >= n) return;
  int f2 = lane & 31, ep = lane >> 5;
  const __half2* xw2 = (const __half2*)xw;
  float ax = 0.f, ay = 0.f;
  int p = row[node], end = row[node+1];

  auto proc = [&](u32 myv, int t){
    u32 v0 = __builtin_amdgcn_readlane(myv, 2*t);
    u32 v1 = __builtin_amdgcn_readlane(myv, 2*t + 1);
    u32 v = ep ? v1 : v0;
    int s = v & 0xFFFF;
    float w = __half2float(__ushort_as_half((unsigned short)(v >> 16)));
    float2 xf = __half22float2(xw2[s*32 + f2]);
    ax = fmaf(w, xf.x, ax);
    ay = fmaf(w, xf.y, ay);
  };

  // rare path: degree >= 64 (P ~ 4e-4 for the whole graph)
  for (; p + 64 <= end; p += 64){
    u32 myv = __builtin_nontemporal_load(&packed[p + lane]);
    #pragma unroll
    for (int t = 0; t < 32; ++t) proc(myv, t);
  }
  // common path: entire (remaining) list in one padded straight-line block
  int rem = end - p;                        // 0..63
  if (rem > 0){
    u32 myv = (lane < rem) ? packed[p + lane] : 0u;
    #pragma unroll
    for (int t = 0; t < 16; ++t) proc(myv, t);      // edges 0..31
    if (rem > 32){
      #pragma unroll
      for (int t = 16; t < 32; ++t) proc(myv, t);   // edges 32..63
    }
  }

  ax += __shfl_xor(ax, 32, 64);                 // combine even/odd edge partials
  ay += __shfl_xor(ay, 32, 64);
  if (ep == 0){
    float di = dinv[node];
    float2 sf = __half22float2(xw2[(size_t)node*32 + f2]);
    float ox = ax + sf.x*(di*di) + b[2*f2];
    float oy = ay + sf.y*(di*di) + b[2*f2 + 1];
    ((__half2*)out)[(size_t)node*32 + f2] = __floats2half2_rn(ox, oy);
  }
}

// scalar agg (wave per node) + Linear(1,1) + build xin = cat(x, xsol)
__global__ void k_agg1_xsol(const int* __restrict__ row, const u32* __restrict__ packed,
                            const float* __restrict__ s0, const float* __restrict__ dinv,
                            const float* __restrict__ b, const float* __restrict__ Wl,
                            const float* __restrict__ bl, const float* __restrict__ x,
                            float* __restrict__ xsol, float* __restrict__ xin, int n){
  int tid = blockIdx.x*256 + threadIdx.x;
  int node = tid >> 6, lane = tid & 63;
  if (node >= n) return;
  int beg = row[node], end = row[node+1];
  float acc = 0.f;
  for (int p = beg + lane; p < end; p += 64){
    u32 v = packed[p];
    float w = __half2float(__ushort_as_half((unsigned short)(v >> 16)));
    acc = fmaf(w, s0[v & 0xFFFF], acc);
  }
  for (int o = 32; o > 0; o >>= 1) acc += __shfl_xor(acc, o, 64);
  if (lane == 0){
    float di = dinv[node];
    float v = s0[node]*(di*di) + b[0] + acc;
    v = v*Wl[0] + bl[0];
    xsol[node] = v;
    float4 xv = ((const float4*)x)[node];
    xin[node*5+0] = xv.x;
    xin[node*5+1] = xv.y;
    xin[node*5+2] = xv.z;
    xin[node*5+3] = xv.w;
    xin[node*5+4] = v;
  }
}

// scalar agg + Linear(1,1) + sigmoid + gated residual combine
__global__ void k_agg1_final(const int* __restrict__ row, const u32* __restrict__ packed,
                             const float* __restrict__ s0, const float* __restrict__ dinv,
                             const float* __restrict__ b, const float* __restrict__ Wl,
                             const float* __restrict__ bl, const float* __restrict__ xsol,
                             const float* __restrict__ x, float* __restrict__ out, int n){
  int tid = blockIdx.x*256 + threadIdx.x;
  int node = tid >> 6, lane = tid & 63;
  if (node >= n) return;
  int beg = row[node], end = row[node+1];
  float acc = 0.f;
  for (int p = beg + lane; p < end; p += 64){
    u32 v = packed[p];
    float w = __half2float(__ushort_as_half((unsigned short)(v >> 16)));
    acc = fmaf(w, s0[v & 0xFFFF], acc);
  }
  for (int o = 32; o > 0; o >>= 1) acc += __shfl_xor(acc, o, 64);
  if (lane == 0){
    float di = dinv[node];
    float g = s0[node]*(di*di) + b[0] + acc;
    g = g*Wl[0] + bl[0];
    float gamma = 1.f / (1.f + expf(-g));
    float xl = x[node*4+3];
    out[node]     = xl + gamma*(xsol[node] - xl);
    out[n + node] = gamma;
  }
}

// ---------------- launch ----------------

extern "C" void kernel_launch(void* const* d_in, const int* in_sizes, int n_in,
                              void* d_out, int out_size, void* d_ws, size_t ws_size,
                              hipStream_t stream){
  const float* x   = (const float*)d_in[0];
  const int*   ei  = (const int*)d_in[1];
  const float* ew  = (const float*)d_in[2];
  const float* oW0 = (const float*)d_in[3];
  const float* ob0 = (const float*)d_in[4];
  const float* oW1 = (const float*)d_in[5];
  const float* ob1 = (const float*)d_in[6];
  const float* oW2 = (const float*)d_in[7];
  const float* ob2 = (const float*)d_in[8];
  const float* oWl = (const float*)d_in[9];
  const float* obl = (const float*)d_in[10];
  const float* gW0 = (const float*)d_in[11];
  const float* gb0 = (const float*)d_in[12];
  const float* gW1 = (const float*)d_in[13];
  const float* gb1 = (const float*)d_in[14];
  const float* gW2 = (const float*)d_in[15];
  const float* gb2 = (const float*)d_in[16];
  const float* gWl = (const float*)d_in[17];
  const float* gbl = (const float*)d_in[18];

  const int n = NN, e = NE;
  const int* src = ei;
  const int* dst = ei + e;

  // workspace layout (8B-aligned blocks first)
  char* wsb = (char*)d_ws;
  int2*  seL    = (int2*)wsb;      wsb += (size_t)e*sizeof(int2);      // 12.8 MB
  u32*   packed = (u32*)wsb;       wsb += (size_t)e*4;                 // 6.4 MB
  __half* bufA  = (__half*)wsb;    wsb += (size_t)n*64*2;              // 6.4 MB ([n][64])
  __half* bufB  = (__half*)wsb;    wsb += (size_t)n*64*2;              // 6.4 MB ([n][64])
  int*   row    = (int*)wsb;       wsb += (size_t)(n+1)*4;
  int*   bcnt   = (int*)wsb;       wsb += 256*4;
  int*   boff   = (int*)wsb;       wsb += 256*4;
  int*   bcur   = (int*)wsb;       wsb += 256*4;
  float* dinv   = (float*)wsb;     wsb += (size_t)n*4;
  float* s0     = (float*)wsb;     wsb += (size_t)n*4;
  float* xsol   = (float*)wsb;     wsb += (size_t)n*4;
  float* xin    = (float*)wsb;     wsb += (size_t)n*5*4;

  dim3 b256(256);
  int gn = cdiv(n, 256);           // 196
  int gw = cdiv(n*64, 256);        // 12500 (wave-per-node kernels)
  int gb = cdiv(e, EPB);           // 391
  int gx = 512;                    // multi-node-wave transform grids
  int gxm = 512;                   // MFMA transform grid

  // ---- CSR build + normalization (shared by all 6 convs) ----
  hipMemsetAsync(bcnt, 0, 256*4, stream);
  k_bcount    <<<gb,  b256, 0, stream>>>(dst, bcnt, e);
  k_scan_bcnt <<<1,   b256, 0, stream>>>(bcnt, boff, bcur, row);
  k_bucket    <<<gb,  b256, 0, stream>>>(src, dst, ew, bcur, seL, e);
  k_csr_bucket<<<NBK, b256, 0, stream>>>(boff, seL, row, packed, dinv, n);
  k_nrm       <<<gw,  b256, 0, stream>>>(row, packed, dinv, n);

  // ---- optim tower: 4 -> 64 -> 64 -> 1, Linear(1,1) ----
  k_xform64f<4>      <<<gx,  b256, 0, stream>>>(x, oW0, bufA, n);
  k_agg64            <<<gw,  b256, 0, stream>>>(row, packed, bufA, dinv, ob0, bufB, n);
  k_xform64_mfma<true><<<gxm, b256, 0, stream>>>(bufB, oW1, bufA, n);
  k_agg64            <<<gw,  b256, 0, stream>>>(row, packed, bufA, dinv, ob1, bufB, n);
  k_xform1h          <<<gw,  b256, 0, stream>>>(bufB, oW2, s0, n);
  k_agg1_xsol        <<<gw,  b256, 0, stream>>>(row, packed, s0, dinv, ob2, oWl, obl, x, xsol, xin, n);

  // ---- gamma tower: 5 -> 64 -> 64 -> 1, Linear(1,1), sigmoid ----
  k_xform64f<5>      <<<gx,  b256, 0, stream>>>(xin, gW0, bufA, n);
  k_agg64            <<<gw,  b256, 0, stream>>>(row, packed, bufA, dinv, gb0, bufB, n);
  k_xform64_mfma<true><<<gxm, b256, 0, stream>>>(bufB, gW1, bufA, n);
  k_agg64            <<<gw,  b256, 0, stream>>>(row, packed, bufA, dinv, gb1, bufB, n);
  k_xform1h          <<<gw,  b256, 0, stream>>>(bufB, gW2, s0, n);
  k_agg1_final       <<<gw,  b256, 0, stream>>>(row, packed, s0, dinv, gb2, gWl, gbl, xsol, x, (float*)d_out, n);
}

// Round 11
// 343.560 us; speedup vs baseline: 2.4175x; 1.1271x over previous
//
#include <hip/hip_runtime.h>
#include <hip/hip_fp16.h>
#include <math.h>

#define NN 50000
#define NE 1600000
#define NBK 196          // buckets of 256 dst-nodes: cdiv(50000,256)
#define EPB 4096         // edges per block in bucket kernels

typedef unsigned int u32;
typedef _Float16 f16x8 __attribute__((ext_vector_type(8)));
typedef float f32x4 __attribute__((ext_vector_type(4)));

static inline int cdiv(int a, int b){ return (a + b - 1) / b; }

// ---------------- CSR build ----------------

__global__ void k_bcount(const int* __restrict__ dst, int* __restrict__ bcnt, int e){
  __shared__ int h[NBK];
  int t = threadIdx.x;
  for (int b = t; b < NBK; b += 256) h[b] = 0;
  __syncthreads();
  int beg = blockIdx.x*EPB, end = min(beg + EPB, e);
  for (int i = beg + t; i < end; i += 256) atomicAdd(&h[dst[i] >> 8], 1);
  __syncthreads();
  for (int b = t; b < NBK; b += 256) if (h[b]) atomicAdd(&bcnt[b], h[b]);
}

// single block: exclusive scan of bucket counts -> boff[0..NBK]; init bcur; row[n]=e
__global__ void k_scan_bcnt(const int* __restrict__ bcnt, int* __restrict__ boff,
                            int* __restrict__ bcur, int* __restrict__ row){
  __shared__ int sh[256];
  int t = threadIdx.x;
  int v = (t < NBK) ? bcnt[t] : 0;
  sh[t] = v; __syncthreads();
  for (int o = 1; o < 256; o <<= 1){
    int u = (t >= o) ? sh[t-o] : 0;
    __syncthreads();
    sh[t] += u;
    __syncthreads();
  }
  int ex = sh[t] - v;
  if (t <= NBK) boff[t] = ex;
  if (t <  NBK) bcur[t] = ex;
  if (t == 0)   row[NN] = NE;
}

// phase A: bin edges by dst>>8; pack dlow into src high bits (src < 65536)
__global__ void k_bucket(const int* __restrict__ src, const int* __restrict__ dst,
                         const float* __restrict__ ew, int* __restrict__ bcur,
                         int2* __restrict__ seL, int e){
  __shared__ int h[NBK], base[NBK], cur[NBK];
  int t = threadIdx.x;
  for (int b = t; b < NBK; b += 256){ h[b] = 0; cur[b] = 0; }
  __syncthreads();
  int beg = blockIdx.x*EPB, end = min(beg + EPB, e);
  for (int i = beg + t; i < end; i += 256) atomicAdd(&h[dst[i] >> 8], 1);
  __syncthreads();
  for (int b = t; b < NBK; b += 256)
    if (h[b] > 0) base[b] = atomicAdd(&bcur[b], h[b]);
  __syncthreads();
  for (int i = beg + t; i < end; i += 256){
    int d = dst[i], b = d >> 8;
    int pos = base[b] + atomicAdd(&cur[b], 1);
    seL[pos] = make_int2(((d & 255) << 16) | src[i], __float_as_int(ew[i]));
  }
}

// phase B: one block per bucket; per-node hist+scan+scatter+deg in LDS.
// packed entry: lo16 = src, hi16 = fp16 edge weight (later overwritten by norm).
__global__ void k_csr_bucket(const int* __restrict__ boff, const int2* __restrict__ seL,
                             int* __restrict__ row, u32* __restrict__ packed,
                             float* __restrict__ dinv, int n){
  __shared__ int hist[256], sh[256], cur[256];
  __shared__ float wsum[256];
  int b = blockIdx.x, t = threadIdx.x;
  int ebeg = boff[b], eend = boff[b+1];
  hist[t] = 0; wsum[t] = 0.f;
  __syncthreads();
  for (int i = ebeg + t; i < eend; i += 256)
    atomicAdd(&hist[seL[i].x >> 16], 1);
  __syncthreads();
  int v = hist[t];
  sh[t] = v; __syncthreads();
  for (int o = 1; o < 256; o <<= 1){
    int u = (t >= o) ? sh[t-o] : 0;
    __syncthreads();
    sh[t] += u;
    __syncthreads();
  }
  int rowv = ebeg + sh[t] - v;
  int node = b*256 + t;
  if (node < n) row[node] = rowv;
  cur[t] = rowv;
  __syncthreads();
  for (int i = ebeg + t; i < eend; i += 256){
    int2 u = seL[i];
    int d = u.x >> 16;
    int pos = atomicAdd(&cur[d], 1);
    float w = __int_as_float(u.y);
    packed[pos] = (u32)(u.x & 0xFFFF) |
                  ((u32)__half_as_ushort(__float2half(w)) << 16);
    atomicAdd(&wsum[d], w);
  }
  __syncthreads();
  if (node < n) dinv[node] = rsqrtf(1.f + wsum[t]);   // deg >= 1 (self-loop)
}

// one wave per node: hi16 of packed := fp16( ew * dinv[src] * dinv[node] )
__global__ void k_nrm(const int* __restrict__ row, u32* __restrict__ packed,
                      const float* __restrict__ dinv, int n){
  int tid = blockIdx.x*256 + threadIdx.x;
  int node = tid >> 6, lane = tid & 63;
  if (node >= n) return;
  float di = dinv[node];
  int beg = row[node], end = row[node+1];
  for (int p = beg + lane; p < end; p += 64){
    u32 v = packed[p];
    int s = v & 0xFFFF;
    float w = __half2float(__ushort_as_half((unsigned short)(v >> 16)));
    w *= di * dinv[s];
    packed[p] = (v & 0xFFFFu) | ((u32)__half_as_ushort(__float2half(w)) << 16);
  }
}

// ---------------- raw-input aggregation (agg commutes with W: agg(xW)=agg(x)W) ----
// thread per node; per edge ONE float4 gather from the 800KB x table (L2-resident)

__global__ void k_agg4(const int* __restrict__ row, const u32* __restrict__ packed,
                       const float* __restrict__ x, const float* __restrict__ dinv,
                       float* __restrict__ y4, int n){
  int i = blockIdx.x*256 + threadIdx.x;
  if (i >= n) return;
  float di = dinv[i];
  float4 self = ((const float4*)x)[i];
  float d2 = di*di;
  float ax = self.x*d2, ay = self.y*d2, az = self.z*d2, aw = self.w*d2;
  int end = row[i+1];
  for (int p = row[i]; p < end; ++p){
    u32 v = packed[p];
    float w = __half2float(__ushort_as_half((unsigned short)(v >> 16)));
    float4 xs = ((const float4*)x)[v & 0xFFFF];
    ax = fmaf(w, xs.x, ax);
    ay = fmaf(w, xs.y, ay);
    az = fmaf(w, xs.z, az);
    aw = fmaf(w, xs.w, aw);
  }
  ((float4*)y4)[i] = make_float4(ax, ay, az, aw);
}

// ---------------- dense transforms ----------------

// fp32 y4 [n,4] -> @W[4,64] + b -> fp16 out [n][64] (pre-relu)
__global__ __launch_bounds__(256, 4)
void k_xform64fb4(const float* __restrict__ y4, const float* __restrict__ W,
                  const float* __restrict__ b, __half* __restrict__ out, int n){
  int j = threadIdx.x & 63;
  int wid = (blockIdx.x*256 + threadIdx.x) >> 6;
  int nw = gridDim.x * 4;
  float w0 = W[j], w1 = W[64 + j], w2 = W[128 + j], w3 = W[192 + j];
  float bj = b[j];
  for (int node = wid; node < n; node += nw){
    float4 r = ((const float4*)y4)[node];
    float acc = bj;
    acc = fmaf(r.x, w0, acc);
    acc = fmaf(r.y, w1, acc);
    acc = fmaf(r.z, w2, acc);
    acc = fmaf(r.w, w3, acc);
    out[(size_t)node*64 + j] = __float2half(acc);
  }
}

// [y4 | yx] (5-dim fp32) -> @W[5,64] + b -> fp16 out [n][64] (pre-relu)
__global__ __launch_bounds__(256, 4)
void k_xform64fb5(const float* __restrict__ y4, const float* __restrict__ yx,
                  const float* __restrict__ W, const float* __restrict__ b,
                  __half* __restrict__ out, int n){
  int j = threadIdx.x & 63;
  int wid = (blockIdx.x*256 + threadIdx.x) >> 6;
  int nw = gridDim.x * 4;
  float w0 = W[j], w1 = W[64 + j], w2 = W[128 + j], w3 = W[192 + j], w4 = W[256 + j];
  float bj = b[j];
  for (int node = wid; node < n; node += nw){
    float4 r = ((const float4*)y4)[node];
    float r4 = yx[node];
    float acc = bj;
    acc = fmaf(r.x, w0, acc);
    acc = fmaf(r.y, w1, acc);
    acc = fmaf(r.z, w2, acc);
    acc = fmaf(r.w, w3, acc);
    acc = fmaf(r4,  w4, acc);
    out[(size_t)node*64 + j] = __float2half(acc);
  }
}

// MFMA transform: fp16 in [n,64] -> relu -> @W[64,64](fp32, cast fp16) ->
// fp16 out [n][64]. One wave = 16-node x 64-feature tile,
// 8x mfma_f32_16x16x32_f16. W in 8 NAMED B-fragments (no indexable array ->
// no scratch spill). Layouts (HW-verified): A[m=lane&15][k=quad*8+j];
// B[k=quad*8+j][col=lane&15]; C/D: col=lane&15, row=quad*4+reg.
template<bool RELU>
__global__ __attribute__((amdgpu_waves_per_eu(2, 4)))
void k_xform64_mfma(const __half* __restrict__ in, const float* __restrict__ W,
                    __half* __restrict__ out, int n){
  int lane = threadIdx.x & 63;
  int m = lane & 15, q = lane >> 4;
  int wid = (blockIdx.x*256 + threadIdx.x) >> 6;
  int nw = gridDim.x * 4;

  auto ldB = [&](int kk, int ct){
    f16x8 r;
    #pragma unroll
    for (int j = 0; j < 8; ++j)
      r[j] = (_Float16)W[(kk*32 + q*8 + j)*64 + ct*16 + m];
    return r;
  };
  f16x8 b00 = ldB(0,0), b01 = ldB(0,1), b02 = ldB(0,2), b03 = ldB(0,3);
  f16x8 b10 = ldB(1,0), b11 = ldB(1,1), b12 = ldB(1,2), b13 = ldB(1,3);

  int ntiles = n >> 4;                         // 50000 = 16*3125 exactly
  for (int tile = wid; tile < ntiles; tile += nw){
    int base = tile << 4;
    const f16x8* arow = (const f16x8*)(in + (size_t)(base + m)*64);
    f16x8 a0 = arow[q];                        // k = q*8 + j        (K-step 0)
    f16x8 a1 = arow[4 + q];                    // k = 32 + q*8 + j   (K-step 1)
    if (RELU){
      #pragma unroll
      for (int i = 0; i < 8; ++i){
        a0[i] = a0[i] > (_Float16)0 ? a0[i] : (_Float16)0;
        a1[i] = a1[i] > (_Float16)0 ? a1[i] : (_Float16)0;
      }
    }
    f32x4 c0 = {0,0,0,0}, c1 = {0,0,0,0}, c2 = {0,0,0,0}, c3 = {0,0,0,0};
    c0 = __builtin_amdgcn_mfma_f32_16x16x32_f16(a0, b00, c0, 0, 0, 0);
    c0 = __builtin_amdgcn_mfma_f32_16x16x32_f16(a1, b10, c0, 0, 0, 0);
    c1 = __builtin_amdgcn_mfma_f32_16x16x32_f16(a0, b01, c1, 0, 0, 0);
    c1 = __builtin_amdgcn_mfma_f32_16x16x32_f16(a1, b11, c1, 0, 0, 0);
    c2 = __builtin_amdgcn_mfma_f32_16x16x32_f16(a0, b02, c2, 0, 0, 0);
    c2 = __builtin_amdgcn_mfma_f32_16x16x32_f16(a1, b12, c2, 0, 0, 0);
    c3 = __builtin_amdgcn_mfma_f32_16x16x32_f16(a0, b03, c3, 0, 0, 0);
    c3 = __builtin_amdgcn_mfma_f32_16x16x32_f16(a1, b13, c3, 0, 0, 0);

    auto st = [&](const f32x4& c, int ct){
      int ft = ct*16 + m;                      // feature = col
      #pragma unroll
      for (int r = 0; r < 4; ++r)              // node = row = base + q*4 + r
        out[(size_t)(base + q*4 + r)*64 + ft] = __float2half(c[r]);
    };
    st(c0, 0); st(c1, 1); st(c2, 2); st(c3, 3);
  }
}

// fp16 input [n,64] -> relu -> @W[64,1] -> fp32 out[n]; wave per node, lane-parallel
__global__ void k_xform1h(const __half* __restrict__ in, const float* __restrict__ W,
                          float* __restrict__ out, int n){
  int tid = blockIdx.x*256 + threadIdx.x;
  int node = tid >> 6, lane = tid & 63;
  if (node >= n) return;
  float w = W[lane];
  float v = fmaxf(__half2float(in[(size_t)node*64 + lane]), 0.f) * w;
  for (int o = 32; o > 0; o >>= 1) v += __shfl_xor(v, o, 64);
  if (lane == 0) out[node] = v;
}

// ---------------- CSR aggregation: 64-feature, single pass, half2 gathers ------
// one wave per node; lane = (edge parity ep, feature-pair f2).
// Poisson(32) in-degree: nearly all nodes have <64 edges -> whole edge list
// handled by a zero-padded FULLY UNROLLED block (16+16 iters, second skipped
// when rem<=32) => ~16 gathers in flight per wave (runtime loop kept ~1 ->
// 59us latency chain, r9). Padded slots: s=0,w=0 -> fma adds 0.
__global__ __attribute__((amdgpu_waves_per_eu(4, 8)))
void k_agg64(const int* __restrict__ row, const u32* __restrict__ packed,
             const __half* __restrict__ xw, const float* __restrict__ dinv,
             const float* __restrict__ b, __half* __restrict__ out, int n){
  int tid = blockIdx.x*256 + threadIdx.x;
  int node = tid >> 6, lane = tid & 63;
  if (node >= n) return;
  int f2 = lane & 31, ep = lane >> 5;
  const __half2* xw2 = (const __half2*)xw;
  float ax = 0.f, ay = 0.f;
  int p = row[node], end = row[node+1];

  auto proc = [&](u32 myv, int t){
    u32 v0 = __builtin_amdgcn_readlane(myv, 2*t);
    u32 v1 = __builtin_amdgcn_readlane(myv, 2*t + 1);
    u32 v = ep ? v1 : v0;
    int s = v & 0xFFFF;
    float w = __half2float(__ushort_as_half((unsigned short)(v >> 16)));
    float2 xf = __half22float2(xw2[s*32 + f2]);
    ax = fmaf(w, xf.x, ax);
    ay = fmaf(w, xf.y, ay);
  };

  // rare path: degree >= 64
  for (; p + 64 <= end; p += 64){
    u32 myv = __builtin_nontemporal_load(&packed[p + lane]);
    #pragma unroll
    for (int t = 0; t < 32; ++t) proc(myv, t);
  }
  // common path: entire (remaining) list in one padded straight-line block
  int rem = end - p;                        // 0..63
  if (rem > 0){
    u32 myv = (lane < rem) ? packed[p + lane] : 0u;
    #pragma unroll
    for (int t = 0; t < 16; ++t) proc(myv, t);      // edges 0..31
    if (rem > 32){
      #pragma unroll
      for (int t = 16; t < 32; ++t) proc(myv, t);   // edges 32..63
    }
  }

  ax += __shfl_xor(ax, 32, 64);                 // combine even/odd edge partials
  ay += __shfl_xor(ay, 32, 64);
  if (ep == 0){
    float di = dinv[node];
    float2 sf = __half22float2(xw2[(size_t)node*32 + f2]);
    float ox = ax + sf.x*(di*di) + b[2*f2];
    float oy = ay + sf.y*(di*di) + b[2*f2 + 1];
    ((__half2*)out)[(size_t)node*32 + f2] = __floats2half2_rn(ox, oy);
  }
}

// scalar agg (wave per node) + conv bias + Linear(1,1) -> xsol
__global__ void k_agg1_xsol(const int* __restrict__ row, const u32* __restrict__ packed,
                            const float* __restrict__ s0, const float* __restrict__ dinv,
                            const float* __restrict__ b, const float* __restrict__ Wl,
                            const float* __restrict__ bl, float* __restrict__ xsol, int n){
  int tid = blockIdx.x*256 + threadIdx.x;
  int node = tid >> 6, lane = tid & 63;
  if (node >= n) return;
  int beg = row[node], end = row[node+1];
  float acc = 0.f;
  for (int p = beg + lane; p < end; p += 64){
    u32 v = packed[p];
    float w = __half2float(__ushort_as_half((unsigned short)(v >> 16)));
    acc = fmaf(w, s0[v & 0xFFFF], acc);
  }
  for (int o = 32; o > 0; o >>= 1) acc += __shfl_xor(acc, o, 64);
  if (lane == 0){
    float di = dinv[node];
    float v = s0[node]*(di*di) + b[0] + acc;
    xsol[node] = v*Wl[0] + bl[0];
  }
}

// plain scalar agg (no bias): yx = dinv^2*xsol + sum nrm*xsol[src]
// (= the 5th channel of agg5(cat(x,xsol)); first 4 channels are tower-1's y4)
__global__ void k_agg1s(const int* __restrict__ row, const u32* __restrict__ packed,
                        const float* __restrict__ xs, const float* __restrict__ dinv,
                        float* __restrict__ yx, int n){
  int tid = blockIdx.x*256 + threadIdx.x;
  int node = tid >> 6, lane = tid & 63;
  if (node >= n) return;
  int beg = row[node], end = row[node+1];
  float acc = 0.f;
  for (int p = beg + lane; p < end; p += 64){
    u32 v = packed[p];
    float w = __half2float(__ushort_as_half((unsigned short)(v >> 16)));
    acc = fmaf(w, xs[v & 0xFFFF], acc);
  }
  for (int o = 32; o > 0; o >>= 1) acc += __shfl_xor(acc, o, 64);
  if (lane == 0){
    float di = dinv[node];
    yx[node] = xs[node]*(di*di) + acc;
  }
}

// scalar agg + Linear(1,1) + sigmoid + gated residual combine
__global__ void k_agg1_final(const int* __restrict__ row, const u32* __restrict__ packed,
                             const float* __restrict__ s0, const float* __restrict__ dinv,
                             const float* __restrict__ b, const float* __restrict__ Wl,
                             const float* __restrict__ bl, const float* __restrict__ xsol,
                             const float* __restrict__ x, float* __restrict__ out, int n){
  int tid = blockIdx.x*256 + threadIdx.x;
  int node = tid >> 6, lane = tid & 63;
  if (node >= n) return;
  int beg = row[node], end = row[node+1];
  float acc = 0.f;
  for (int p = beg + lane; p < end; p += 64){
    u32 v = packed[p];
    float w = __half2float(__ushort_as_half((unsigned short)(v >> 16)));
    acc = fmaf(w, s0[v & 0xFFFF], acc);
  }
  for (int o = 32; o > 0; o >>= 1) acc += __shfl_xor(acc, o, 64);
  if (lane == 0){
    float di = dinv[node];
    float g = s0[node]*(di*di) + b[0] + acc;
    g = g*Wl[0] + bl[0];
    float gamma = 1.f / (1.f + expf(-g));
    float xl = x[node*4+3];
    out[node]     = xl + gamma*(xsol[node] - xl);
    out[n + node] = gamma;
  }
}

// ---------------- launch ----------------

extern "C" void kernel_launch(void* const* d_in, const int* in_sizes, int n_in,
                              void* d_out, int out_size, void* d_ws, size_t ws_size,
                              hipStream_t stream){
  const float* x   = (const float*)d_in[0];
  const int*   ei  = (const int*)d_in[1];
  const float* ew  = (const float*)d_in[2];
  const float* oW0 = (const float*)d_in[3];
  const float* ob0 = (const float*)d_in[4];
  const float* oW1 = (const float*)d_in[5];
  const float* ob1 = (const float*)d_in[6];
  const float* oW2 = (const float*)d_in[7];
  const float* ob2 = (const float*)d_in[8];
  const float* oWl = (const float*)d_in[9];
  const float* obl = (const float*)d_in[10];
  const float* gW0 = (const float*)d_in[11];
  const float* gb0 = (const float*)d_in[12];
  const float* gW1 = (const float*)d_in[13];
  const float* gb1 = (const float*)d_in[14];
  const float* gW2 = (const float*)d_in[15];
  const float* gb2 = (const float*)d_in[16];
  const float* gWl = (const float*)d_in[17];
  const float* gbl = (const float*)d_in[18];

  const int n = NN, e = NE;
  const int* src = ei;
  const int* dst = ei + e;

  // workspace layout (8B-aligned blocks first)
  char* wsb = (char*)d_ws;
  int2*  seL    = (int2*)wsb;      wsb += (size_t)e*sizeof(int2);      // 12.8 MB
  u32*   packed = (u32*)wsb;       wsb += (size_t)e*4;                 // 6.4 MB
  __half* bufA  = (__half*)wsb;    wsb += (size_t)n*64*2;              // 6.4 MB ([n][64])
  __half* bufB  = (__half*)wsb;    wsb += (size_t)n*64*2;              // 6.4 MB ([n][64])
  float* y4     = (float*)wsb;     wsb += (size_t)n*4*4;               // 800 KB
  int*   row    = (int*)wsb;       wsb += (size_t)(n+1)*4;
  int*   bcnt   = (int*)wsb;       wsb += 256*4;
  int*   boff   = (int*)wsb;       wsb += 256*4;
  int*   bcur   = (int*)wsb;       wsb += 256*4;
  float* dinv   = (float*)wsb;     wsb += (size_t)n*4;
  float* s0     = (float*)wsb;     wsb += (size_t)n*4;
  float* xsol   = (float*)wsb;     wsb += (size_t)n*4;
  float* yx     = (float*)wsb;     wsb += (size_t)n*4;

  dim3 b256(256);
  int gn = cdiv(n, 256);           // 196
  int gw = cdiv(n*64, 256);        // 12500 (wave-per-node kernels)
  int gb = cdiv(e, EPB);           // 391
  int gx = 512;                    // multi-node-wave transform grids
  int gxm = 512;                   // MFMA transform grid

  // ---- CSR build + normalization (shared by all 6 convs) ----
  hipMemsetAsync(bcnt, 0, 256*4, stream);
  k_bcount    <<<gb,  b256, 0, stream>>>(dst, bcnt, e);
  k_scan_bcnt <<<1,   b256, 0, stream>>>(bcnt, boff, bcur, row);
  k_bucket    <<<gb,  b256, 0, stream>>>(src, dst, ew, bcur, seL, e);
  k_csr_bucket<<<NBK, b256, 0, stream>>>(boff, seL, row, packed, dinv, n);
  k_nrm       <<<gw,  b256, 0, stream>>>(row, packed, dinv, n);

  // shared raw-x aggregation (used by BOTH towers' layer 1)
  k_agg4      <<<gn,  b256, 0, stream>>>(row, packed, x, dinv, y4, n);

  // ---- optim tower: conv1 = agg4(x)@W0+b0; conv2; conv3; Linear(1,1) ----
  k_xform64fb4       <<<gx,  b256, 0, stream>>>(y4, oW0, ob0, bufB, n);
  k_xform64_mfma<true><<<gxm, b256, 0, stream>>>(bufB, oW1, bufA, n);
  k_agg64            <<<gw,  b256, 0, stream>>>(row, packed, bufA, dinv, ob1, bufB, n);
  k_xform1h          <<<gw,  b256, 0, stream>>>(bufB, oW2, s0, n);
  k_agg1_xsol        <<<gw,  b256, 0, stream>>>(row, packed, s0, dinv, ob2, oWl, obl, xsol, n);

  // ---- gamma tower: agg5(cat(x,xsol)) = [y4 | agg1(xsol)] ----
  k_agg1s            <<<gw,  b256, 0, stream>>>(row, packed, xsol, dinv, yx, n);
  k_xform64fb5       <<<gx,  b256, 0, stream>>>(y4, yx, gW0, gb0, bufB, n);
  k_xform64_mfma<true><<<gxm, b256, 0, stream>>>(bufB, gW1, bufA, n);
  k_agg64            <<<gw,  b256, 0, stream>>>(row, packed, bufA, dinv, gb1, bufB, n);
  k_xform1h          <<<gw,  b256, 0, stream>>>(bufB, gW2, s0, n);
  k_agg1_final       <<<gw,  b256, 0, stream>>>(row, packed, s0, dinv, gb2, gWl, gbl, xsol, x, (float*)d_out, n);
}

// Round 12
// 322.797 us; speedup vs baseline: 2.5730x; 1.0643x over previous
//
#include <hip/hip_runtime.h>
#include <hip/hip_fp16.h>
#include <math.h>

#define NN 50000
#define NE 1600000
#define NBK 196          // buckets of 256 dst-nodes: cdiv(50000,256)
#define EPB 4096         // edges per block in bucket kernels

typedef unsigned int u32;
typedef _Float16 f16x8 __attribute__((ext_vector_type(8)));
typedef float f32x4 __attribute__((ext_vector_type(4)));

static inline int cdiv(int a, int b){ return (a + b - 1) / b; }

// D-scaling convention: every stored feature tensor is S = dinv (.) H.
// GCN layer: H' = D(A+I)D H + b  =  dinv_d * ( sum_e ew*S[src] + S[d] ) + b.
// relu(dinv*v) = dinv*relu(v) (dinv>0), so relu commutes with the convention.
// => edges carry RAW fp16(ew); no per-edge norm pass (k_nrm deleted).

// ---------------- CSR build ----------------

__global__ void k_bcount(const int* __restrict__ dst, int* __restrict__ bcnt, int e){
  __shared__ int h[NBK];
  int t = threadIdx.x;
  for (int b = t; b < NBK; b += 256) h[b] = 0;
  __syncthreads();
  int beg = blockIdx.x*EPB, end = min(beg + EPB, e);
  for (int i = beg + t; i < end; i += 256) atomicAdd(&h[dst[i] >> 8], 1);
  __syncthreads();
  for (int b = t; b < NBK; b += 256) if (h[b]) atomicAdd(&bcnt[b], h[b]);
}

// single block: exclusive scan of bucket counts -> boff[0..NBK]; init bcur; row[n]=e
__global__ void k_scan_bcnt(const int* __restrict__ bcnt, int* __restrict__ boff,
                            int* __restrict__ bcur, int* __restrict__ row){
  __shared__ int sh[256];
  int t = threadIdx.x;
  int v = (t < NBK) ? bcnt[t] : 0;
  sh[t] = v; __syncthreads();
  for (int o = 1; o < 256; o <<= 1){
    int u = (t >= o) ? sh[t-o] : 0;
    __syncthreads();
    sh[t] += u;
    __syncthreads();
  }
  int ex = sh[t] - v;
  if (t <= NBK) boff[t] = ex;
  if (t <  NBK) bcur[t] = ex;
  if (t == 0)   row[NN] = NE;
}

// phase A: bin edges by dst>>8; pack dlow into src high bits (src < 65536)
__global__ void k_bucket(const int* __restrict__ src, const int* __restrict__ dst,
                         const float* __restrict__ ew, int* __restrict__ bcur,
                         int2* __restrict__ seL, int e){
  __shared__ int h[NBK], base[NBK], cur[NBK];
  int t = threadIdx.x;
  for (int b = t; b < NBK; b += 256){ h[b] = 0; cur[b] = 0; }
  __syncthreads();
  int beg = blockIdx.x*EPB, end = min(beg + EPB, e);
  for (int i = beg + t; i < end; i += 256) atomicAdd(&h[dst[i] >> 8], 1);
  __syncthreads();
  for (int b = t; b < NBK; b += 256)
    if (h[b] > 0) base[b] = atomicAdd(&bcur[b], h[b]);
  __syncthreads();
  for (int i = beg + t; i < end; i += 256){
    int d = dst[i], b = d >> 8;
    int pos = base[b] + atomicAdd(&cur[b], 1);
    seL[pos] = make_int2(((d & 255) << 16) | src[i], __float_as_int(ew[i]));
  }
}

// phase B: one block per bucket; per-node hist+scan+scatter+deg in LDS.
// packed entry: lo16 = src, hi16 = fp16(ew) (raw; D-convention needs no norm).
// tail also emits dinv and xd = dinv (.) x (fp32, layer-1 gather table).
__global__ void k_csr_bucket(const int* __restrict__ boff, const int2* __restrict__ seL,
                             const float* __restrict__ x, int* __restrict__ row,
                             u32* __restrict__ packed, float* __restrict__ dinv,
                             float* __restrict__ xd, int n){
  __shared__ int hist[256], sh[256], cur[256];
  __shared__ float wsum[256];
  int b = blockIdx.x, t = threadIdx.x;
  int ebeg = boff[b], eend = boff[b+1];
  hist[t] = 0; wsum[t] = 0.f;
  __syncthreads();
  for (int i = ebeg + t; i < eend; i += 256)
    atomicAdd(&hist[seL[i].x >> 16], 1);
  __syncthreads();
  int v = hist[t];
  sh[t] = v; __syncthreads();
  for (int o = 1; o < 256; o <<= 1){
    int u = (t >= o) ? sh[t-o] : 0;
    __syncthreads();
    sh[t] += u;
    __syncthreads();
  }
  int rowv = ebeg + sh[t] - v;
  int node = b*256 + t;
  if (node < n) row[node] = rowv;
  cur[t] = rowv;
  __syncthreads();
  for (int i = ebeg + t; i < eend; i += 256){
    int2 u = seL[i];
    int d = u.x >> 16;
    int pos = atomicAdd(&cur[d], 1);
    float w = __int_as_float(u.y);
    packed[pos] = (u32)(u.x & 0xFFFF) |
                  ((u32)__half_as_ushort(__float2half(w)) << 16);
    atomicAdd(&wsum[d], w);
  }
  __syncthreads();
  if (node < n){
    float di = rsqrtf(1.f + wsum[t]);   // deg >= 1 (self-loop)
    dinv[node] = di;
    float4 xv = ((const float4*)x)[node];
    ((float4*)xd)[node] = make_float4(xv.x*di, xv.y*di, xv.z*di, xv.w*di);
  }
}

// ---------------- raw-input aggregation: y4 = D(A+I)D x = D(A_e xd + xd) ------
// thread per node; per edge ONE float4 gather from the 800KB xd table

__global__ void k_agg4(const int* __restrict__ row, const u32* __restrict__ packed,
                       const float* __restrict__ xd, const float* __restrict__ dinv,
                       float* __restrict__ y4, int n){
  int i = blockIdx.x*256 + threadIdx.x;
  if (i >= n) return;
  float4 self = ((const float4*)xd)[i];
  float ax = self.x, ay = self.y, az = self.z, aw = self.w;
  int end = row[i+1];
  for (int p = row[i]; p < end; ++p){
    u32 v = packed[p];
    float w = __half2float(__ushort_as_half((unsigned short)(v >> 16)));
    float4 xs = ((const float4*)xd)[v & 0xFFFF];
    ax = fmaf(w, xs.x, ax);
    ay = fmaf(w, xs.y, ay);
    az = fmaf(w, xs.z, az);
    aw = fmaf(w, xs.w, aw);
  }
  float di = dinv[i];
  ((float4*)y4)[i] = make_float4(ax*di, ay*di, az*di, aw*di);
}

// ---------------- dense transforms ----------------

// fp32 y4 [n,4] -> @W[4,64] + b -> fp16 out [n][64] (h1, true conv output)
__global__ __launch_bounds__(256, 4)
void k_xform64fb4(const float* __restrict__ y4, const float* __restrict__ W,
                  const float* __restrict__ b, __half* __restrict__ out, int n){
  int j = threadIdx.x & 63;
  int wid = (blockIdx.x*256 + threadIdx.x) >> 6;
  int nw = gridDim.x * 4;
  float w0 = W[j], w1 = W[64 + j], w2 = W[128 + j], w3 = W[192 + j];
  float bj = b[j];
  for (int node = wid; node < n; node += nw){
    float4 r = ((const float4*)y4)[node];
    float acc = bj;
    acc = fmaf(r.x, w0, acc);
    acc = fmaf(r.y, w1, acc);
    acc = fmaf(r.z, w2, acc);
    acc = fmaf(r.w, w3, acc);
    out[(size_t)node*64 + j] = __float2half(acc);
  }
}

// [y4 | yx] (5-dim fp32) -> @W[5,64] + b -> fp16 out [n][64]
__global__ __launch_bounds__(256, 4)
void k_xform64fb5(const float* __restrict__ y4, const float* __restrict__ yx,
                  const float* __restrict__ W, const float* __restrict__ b,
                  __half* __restrict__ out, int n){
  int j = threadIdx.x & 63;
  int wid = (blockIdx.x*256 + threadIdx.x) >> 6;
  int nw = gridDim.x * 4;
  float w0 = W[j], w1 = W[64 + j], w2 = W[128 + j], w3 = W[192 + j], w4 = W[256 + j];
  float bj = b[j];
  for (int node = wid; node < n; node += nw){
    float4 r = ((const float4*)y4)[node];
    float r4 = yx[node];
    float acc = bj;
    acc = fmaf(r.x, w0, acc);
    acc = fmaf(r.y, w1, acc);
    acc = fmaf(r.z, w2, acc);
    acc = fmaf(r.w, w3, acc);
    acc = fmaf(r4,  w4, acc);
    out[(size_t)node*64 + j] = __float2half(acc);
  }
}

// MFMA transform: fp16 h [n,64] -> relu -> @W[64,64] -> *dinv_row -> fp16 out.
// Output is pre-scaled by D (u_hat), ready for raw-ew aggregation.
// One wave = 16-node x 64-feature tile, 8x mfma_f32_16x16x32_f16; W in 8
// NAMED B-fragments (no indexable array -> no scratch spill).
// Layouts (HW-verified): A[m=lane&15][k=quad*8+j]; B[k=quad*8+j][col=lane&15];
// C/D: col=lane&15, row=quad*4+reg.
__global__ __attribute__((amdgpu_waves_per_eu(2, 4)))
void k_xform64_mfma(const __half* __restrict__ in, const float* __restrict__ W,
                    const float* __restrict__ dinv, __half* __restrict__ out, int n){
  int lane = threadIdx.x & 63;
  int m = lane & 15, q = lane >> 4;
  int wid = (blockIdx.x*256 + threadIdx.x) >> 6;
  int nw = gridDim.x * 4;

  auto ldB = [&](int kk, int ct){
    f16x8 r;
    #pragma unroll
    for (int j = 0; j < 8; ++j)
      r[j] = (_Float16)W[(kk*32 + q*8 + j)*64 + ct*16 + m];
    return r;
  };
  f16x8 b00 = ldB(0,0), b01 = ldB(0,1), b02 = ldB(0,2), b03 = ldB(0,3);
  f16x8 b10 = ldB(1,0), b11 = ldB(1,1), b12 = ldB(1,2), b13 = ldB(1,3);

  int ntiles = n >> 4;                         // 50000 = 16*3125 exactly
  for (int tile = wid; tile < ntiles; tile += nw){
    int base = tile << 4;
    const f16x8* arow = (const f16x8*)(in + (size_t)(base + m)*64);
    f16x8 a0 = arow[q];                        // k = q*8 + j        (K-step 0)
    f16x8 a1 = arow[4 + q];                    // k = 32 + q*8 + j   (K-step 1)
    #pragma unroll
    for (int i = 0; i < 8; ++i){               // relu
      a0[i] = a0[i] > (_Float16)0 ? a0[i] : (_Float16)0;
      a1[i] = a1[i] > (_Float16)0 ? a1[i] : (_Float16)0;
    }
    f32x4 c0 = {0,0,0,0}, c1 = {0,0,0,0}, c2 = {0,0,0,0}, c3 = {0,0,0,0};
    c0 = __builtin_amdgcn_mfma_f32_16x16x32_f16(a0, b00, c0, 0, 0, 0);
    c0 = __builtin_amdgcn_mfma_f32_16x16x32_f16(a1, b10, c0, 0, 0, 0);
    c1 = __builtin_amdgcn_mfma_f32_16x16x32_f16(a0, b01, c1, 0, 0, 0);
    c1 = __builtin_amdgcn_mfma_f32_16x16x32_f16(a1, b11, c1, 0, 0, 0);
    c2 = __builtin_amdgcn_mfma_f32_16x16x32_f16(a0, b02, c2, 0, 0, 0);
    c2 = __builtin_amdgcn_mfma_f32_16x16x32_f16(a1, b12, c2, 0, 0, 0);
    c3 = __builtin_amdgcn_mfma_f32_16x16x32_f16(a0, b03, c3, 0, 0, 0);
    c3 = __builtin_amdgcn_mfma_f32_16x16x32_f16(a1, b13, c3, 0, 0, 0);

    float4 dv = ((const float4*)dinv)[tile*4 + q];   // rows base+q*4 .. +3
    float dvr[4] = {dv.x, dv.y, dv.z, dv.w};         // const-indexed, promoted
    auto st = [&](const f32x4& c, int ct){
      int ft = ct*16 + m;                      // feature = col
      #pragma unroll
      for (int r = 0; r < 4; ++r)              // node = row = base + q*4 + r
        out[(size_t)(base + q*4 + r)*64 + ft] = __float2half(c[r]*dvr[r]);
    };
    st(c0, 0); st(c1, 1); st(c2, 2); st(c3, 3);
  }
}

// ---------------- fused conv-agg + bias + relu + @W2 + D-scale ----------------
// one wave per node; lane = (edge parity ep, feature-pair f2).
// t = sum_e ew*u_hat[src] + u_hat[node]; h = dinv*t + b; s = relu(h)@W2;
// writes s_hat = dinv*s (fp32, 200KB) -- the next agg's gather table.
// Poisson(32) degree: whole edge list via zero-padded FULLY UNROLLED block
// (~16 gathers in flight; runtime loop kept ~1 -> 59us latency chain, r9).
__global__ __attribute__((amdgpu_waves_per_eu(4, 8)))
void k_agg64f(const int* __restrict__ row, const u32* __restrict__ packed,
              const __half* __restrict__ xw, const float* __restrict__ dinv,
              const float* __restrict__ b, const float* __restrict__ W2,
              float* __restrict__ shat, int n){
  int tid = blockIdx.x*256 + threadIdx.x;
  int node = tid >> 6, lane = tid & 63;
  if (node >= n) return;
  int f2 = lane & 31, ep = lane >> 5;
  const __half2* xw2 = (const __half2*)xw;
  float ax = 0.f, ay = 0.f;
  int p = row[node], end = row[node+1];

  auto proc = [&](u32 myv, int t){
    u32 v0 = __builtin_amdgcn_readlane(myv, 2*t);
    u32 v1 = __builtin_amdgcn_readlane(myv, 2*t + 1);
    u32 v = ep ? v1 : v0;
    int s = v & 0xFFFF;
    float w = __half2float(__ushort_as_half((unsigned short)(v >> 16)));
    float2 xf = __half22float2(xw2[s*32 + f2]);
    ax = fmaf(w, xf.x, ax);
    ay = fmaf(w, xf.y, ay);
  };

  // rare path: degree >= 64
  for (; p + 64 <= end; p += 64){
    u32 myv = __builtin_nontemporal_load(&packed[p + lane]);
    #pragma unroll
    for (int t = 0; t < 32; ++t) proc(myv, t);
  }
  // common path: entire (remaining) list in one padded straight-line block
  int rem = end - p;                        // 0..63
  if (rem > 0){
    u32 myv = (lane < rem) ? packed[p + lane] : 0u;   // pad: s=0,w=0 -> adds 0
    #pragma unroll
    for (int t = 0; t < 16; ++t) proc(myv, t);
    if (rem > 32){
      #pragma unroll
      for (int t = 16; t < 32; ++t) proc(myv, t);
    }
  }

  ax += __shfl_xor(ax, 32, 64);                 // combine even/odd edge partials
  ay += __shfl_xor(ay, 32, 64);
  float di = dinv[node];
  float2 sf = __half22float2(xw2[(size_t)node*32 + f2]);   // self term u_hat[d]
  float hx = (ax + sf.x)*di + b[2*f2];
  float hy = (ay + sf.y)*di + b[2*f2 + 1];
  float2 w2 = ((const float2*)W2)[f2];
  float part = fmaxf(hx, 0.f)*w2.x + fmaxf(hy, 0.f)*w2.y;
  part += __shfl_xor(part, 16, 64);             // reduce 32 feature-pairs
  part += __shfl_xor(part, 8, 64);
  part += __shfl_xor(part, 4, 64);
  part += __shfl_xor(part, 2, 64);
  part += __shfl_xor(part, 1, 64);
  if (lane == 0) shat[node] = part * di;        // pre-scaled for next agg
}

// scalar agg of s_hat + conv bias + Linear(1,1) -> xsol (true) and xsol_hat
__global__ void k_agg1_xsol(const int* __restrict__ row, const u32* __restrict__ packed,
                            const float* __restrict__ shat, const float* __restrict__ dinv,
                            const float* __restrict__ b, const float* __restrict__ Wl,
                            const float* __restrict__ bl, float* __restrict__ xsol,
                            float* __restrict__ xsolh, int n){
  int tid = blockIdx.x*256 + threadIdx.x;
  int node = tid >> 6, lane = tid & 63;
  if (node >= n) return;
  int beg = row[node], end = row[node+1];
  float acc = 0.f;
  for (int p = beg + lane; p < end; p += 64){
    u32 v = packed[p];
    float w = __half2float(__ushort_as_half((unsigned short)(v >> 16)));
    acc = fmaf(w, shat[v & 0xFFFF], acc);
  }
  for (int o = 32; o > 0; o >>= 1) acc += __shfl_xor(acc, o, 64);
  if (lane == 0){
    float di = dinv[node];
    float h = (acc + shat[node])*di + b[0];
    float v = h*Wl[0] + bl[0];
    xsol[node]  = v;
    xsolh[node] = v*di;
  }
}

// scalar agg of xsol_hat: yx = dinv*( sum ew*xsolh[s] + xsolh[d] )
// (= 5th channel of agg5(cat(x,xsol)); first 4 channels are y4)
__global__ void k_agg1s(const int* __restrict__ row, const u32* __restrict__ packed,
                        const float* __restrict__ xsh, const float* __restrict__ dinv,
                        float* __restrict__ yx, int n){
  int tid = blockIdx.x*256 + threadIdx.x;
  int node = tid >> 6, lane = tid & 63;
  if (node >= n) return;
  int beg = row[node], end = row[node+1];
  float acc = 0.f;
  for (int p = beg + lane; p < end; p += 64){
    u32 v = packed[p];
    float w = __half2float(__ushort_as_half((unsigned short)(v >> 16)));
    acc = fmaf(w, xsh[v & 0xFFFF], acc);
  }
  for (int o = 32; o > 0; o >>= 1) acc += __shfl_xor(acc, o, 64);
  if (lane == 0)
    yx[node] = (acc + xsh[node]) * dinv[node];
}

// scalar agg of s_hat + bias + Linear(1,1) + sigmoid + gated residual combine
__global__ void k_agg1_final(const int* __restrict__ row, const u32* __restrict__ packed,
                             const float* __restrict__ shat, const float* __restrict__ dinv,
                             const float* __restrict__ b, const float* __restrict__ Wl,
                             const float* __restrict__ bl, const float* __restrict__ xsol,
                             const float* __restrict__ x, float* __restrict__ out, int n){
  int tid = blockIdx.x*256 + threadIdx.x;
  int node = tid >> 6, lane = tid & 63;
  if (node >= n) return;
  int beg = row[node], end = row[node+1];
  float acc = 0.f;
  for (int p = beg + lane; p < end; p += 64){
    u32 v = packed[p];
    float w = __half2float(__ushort_as_half((unsigned short)(v >> 16)));
    acc = fmaf(w, shat[v & 0xFFFF], acc);
  }
  for (int o = 32; o > 0; o >>= 1) acc += __shfl_xor(acc, o, 64);
  if (lane == 0){
    float di = dinv[node];
    float g = ((acc + shat[node])*di + b[0])*Wl[0] + bl[0];
    float gamma = 1.f / (1.f + expf(-g));
    float xl = x[node*4+3];
    out[node]     = xl + gamma*(xsol[node] - xl);
    out[n + node] = gamma;
  }
}

// ---------------- launch ----------------

extern "C" void kernel_launch(void* const* d_in, const int* in_sizes, int n_in,
                              void* d_out, int out_size, void* d_ws, size_t ws_size,
                              hipStream_t stream){
  const float* x   = (const float*)d_in[0];
  const int*   ei  = (const int*)d_in[1];
  const float* ew  = (const float*)d_in[2];
  const float* oW0 = (const float*)d_in[3];
  const float* ob0 = (const float*)d_in[4];
  const float* oW1 = (const float*)d_in[5];
  const float* ob1 = (const float*)d_in[6];
  const float* oW2 = (const float*)d_in[7];
  const float* ob2 = (const float*)d_in[8];
  const float* oWl = (const float*)d_in[9];
  const float* obl = (const float*)d_in[10];
  const float* gW0 = (const float*)d_in[11];
  const float* gb0 = (const float*)d_in[12];
  const float* gW1 = (const float*)d_in[13];
  const float* gb1 = (const float*)d_in[14];
  const float* gW2 = (const float*)d_in[15];
  const float* gb2 = (const float*)d_in[16];
  const float* gWl = (const float*)d_in[17];
  const float* gbl = (const float*)d_in[18];

  const int n = NN, e = NE;
  const int* src = ei;
  const int* dst = ei + e;

  // workspace layout (8B-aligned blocks first)
  char* wsb = (char*)d_ws;
  int2*  seL    = (int2*)wsb;      wsb += (size_t)e*sizeof(int2);      // 12.8 MB
  u32*   packed = (u32*)wsb;       wsb += (size_t)e*4;                 // 6.4 MB
  __half* bufA  = (__half*)wsb;    wsb += (size_t)n*64*2;              // 6.4 MB (u_hat)
  __half* bufB  = (__half*)wsb;    wsb += (size_t)n*64*2;              // 6.4 MB (h1)
  float* y4     = (float*)wsb;     wsb += (size_t)n*4*4;               // 800 KB
  float* xd     = (float*)wsb;     wsb += (size_t)n*4*4;               // 800 KB
  int*   row    = (int*)wsb;       wsb += (size_t)(n+1)*4;
  int*   bcnt   = (int*)wsb;       wsb += 256*4;
  int*   boff   = (int*)wsb;       wsb += 256*4;
  int*   bcur   = (int*)wsb;       wsb += 256*4;
  float* dinv   = (float*)wsb;     wsb += (size_t)n*4;
  float* shat   = (float*)wsb;     wsb += (size_t)n*4;
  float* xsol   = (float*)wsb;     wsb += (size_t)n*4;
  float* xsolh  = (float*)wsb;     wsb += (size_t)n*4;
  float* yx     = (float*)wsb;     wsb += (size_t)n*4;

  dim3 b256(256);
  int gn = cdiv(n, 256);           // 196
  int gw = cdiv(n*64, 256);        // 12500 (wave-per-node kernels)
  int gb = cdiv(e, EPB);           // 391
  int gx = 512;                    // multi-node-wave transform grids
  int gxm = 512;                   // MFMA transform grid

  // ---- CSR build (shared by all 6 convs); emits dinv and xd = dinv(.)x ----
  hipMemsetAsync(bcnt, 0, 256*4, stream);
  k_bcount    <<<gb,  b256, 0, stream>>>(dst, bcnt, e);
  k_scan_bcnt <<<1,   b256, 0, stream>>>(bcnt, boff, bcur, row);
  k_bucket    <<<gb,  b256, 0, stream>>>(src, dst, ew, bcur, seL, e);
  k_csr_bucket<<<NBK, b256, 0, stream>>>(boff, seL, x, row, packed, dinv, xd, n);

  // shared raw-x aggregation (both towers' layer 1)
  k_agg4      <<<gn,  b256, 0, stream>>>(row, packed, xd, dinv, y4, n);

  // ---- optim tower ----
  k_xform64fb4  <<<gx,  b256, 0, stream>>>(y4, oW0, ob0, bufB, n);
  k_xform64_mfma<<<gxm, b256, 0, stream>>>(bufB, oW1, dinv, bufA, n);
  k_agg64f      <<<gw,  b256, 0, stream>>>(row, packed, bufA, dinv, ob1, oW2, shat, n);
  k_agg1_xsol   <<<gw,  b256, 0, stream>>>(row, packed, shat, dinv, ob2, oWl, obl, xsol, xsolh, n);

  // ---- gamma tower: agg5(cat(x,xsol)) = [y4 | agg1(xsol)] ----
  k_agg1s       <<<gw,  b256, 0, stream>>>(row, packed, xsolh, dinv, yx, n);
  k_xform64fb5  <<<gx,  b256, 0, stream>>>(y4, yx, gW0, gb0, bufB, n);
  k_xform64_mfma<<<gxm, b256, 0, stream>>>(bufB, gW1, dinv, bufA, n);
  k_agg64f      <<<gw,  b256, 0, stream>>>(row, packed, bufA, dinv, gb1, gW2, shat, n);
  k_agg1_final  <<<gw,  b256, 0, stream>>>(row, packed, shat, dinv, gb2, gWl, gbl, xsol, x, (float*)d_out, n);
}

// Round 13
// 294.976 us; speedup vs baseline: 2.8157x; 1.0943x over previous
//
#include <hip/hip_runtime.h>
#include <hip/hip_fp16.h>
#include <math.h>

#define NN 50000
#define NE 1600000
#define NBK 196          // buckets of 256 dst-nodes: cdiv(50000,256)
#define EPB 4096         // edges per block in k_bucket (= 16 per thread)
#define CAP 9216         // per-bucket capacity; mean 8163, sigma~90 -> 11σ margin

typedef unsigned int u32;
typedef _Float16 f16x8 __attribute__((ext_vector_type(8)));
typedef float f32x4 __attribute__((ext_vector_type(4)));

static inline int cdiv(int a, int b){ return (a + b - 1) / b; }

// D-scaling convention: every stored feature tensor is S = dinv (.) H.
// GCN layer: H' = dinv_d * ( sum_e ew*S[src] + S[d] ) + b; relu commutes (dinv>0).
// Edges carry RAW fp16(ew). Buckets are fixed-capacity bins (no global scan).

// ---------------- CSR build ----------------

// single pass: hist (dst kept in regs) -> reserve -> scatter into padded bins
__global__ void k_bucket(const int* __restrict__ src, const int* __restrict__ dst,
                         const float* __restrict__ ew, int* __restrict__ bcur,
                         int2* __restrict__ seL, int e){
  __shared__ int h[NBK], base[NBK], curL[NBK];
  int t = threadIdx.x;
  for (int b = t; b < NBK; b += 256){ h[b] = 0; curL[b] = 0; }
  __syncthreads();
  int beg = blockIdx.x*EPB;
  int d[16];
  #pragma unroll
  for (int i = 0; i < 16; ++i){
    int idx = beg + t + i*256;
    d[i] = (idx < e) ? dst[idx] : -1;
    if (d[i] >= 0) atomicAdd(&h[d[i] >> 8], 1);
  }
  __syncthreads();
  for (int b = t; b < NBK; b += 256)
    if (h[b] > 0) base[b] = b*CAP + atomicAdd(&bcur[b], h[b]);   // bcur zero-init
  __syncthreads();
  #pragma unroll
  for (int i = 0; i < 16; ++i){
    int idx = beg + t + i*256;
    if (idx >= e) continue;
    int dd = d[i], b = dd >> 8;
    int pos = base[b] + atomicAdd(&curL[b], 1);
    seL[pos] = make_int2(((dd & 255) << 16) | src[idx], __float_as_int(ew[idx]));
  }
}

// one block per bucket; per-node hist+scan+scatter+deg in LDS.
// packed entry: lo16 = src, hi16 = fp16(ew). Emits rowS/rowE, dinv, xd=dinv(.)x.
__global__ void k_csr_bucket(const int* __restrict__ bcur, const int2* __restrict__ seL,
                             const float* __restrict__ x, int* __restrict__ rowS,
                             int* __restrict__ rowE, u32* __restrict__ packed,
                             float* __restrict__ dinv, float* __restrict__ xd, int n){
  __shared__ int hist[256], sh[256], cur[256];
  __shared__ float wsum[256];
  int b = blockIdx.x, t = threadIdx.x;
  int ebeg = b*CAP, eend = ebeg + bcur[b];
  hist[t] = 0; wsum[t] = 0.f;
  __syncthreads();
  for (int i = ebeg + t; i < eend; i += 256)
    atomicAdd(&hist[seL[i].x >> 16], 1);
  __syncthreads();
  int v = hist[t];
  sh[t] = v; __syncthreads();
  for (int o = 1; o < 256; o <<= 1){
    int u = (t >= o) ? sh[t-o] : 0;
    __syncthreads();
    sh[t] += u;
    __syncthreads();
  }
  int rs = ebeg + sh[t] - v;
  int node = b*256 + t;
  if (node < n){ rowS[node] = rs; rowE[node] = rs + v; }
  cur[t] = rs;
  __syncthreads();
  for (int i = ebeg + t; i < eend; i += 256){
    int2 u = seL[i];
    int d = u.x >> 16;
    int pos = atomicAdd(&cur[d], 1);
    float w = __int_as_float(u.y);
    packed[pos] = (u32)(u.x & 0xFFFF) |
                  ((u32)__half_as_ushort(__float2half(w)) << 16);
    atomicAdd(&wsum[d], w);
  }
  __syncthreads();
  if (node < n){
    float di = rsqrtf(1.f + wsum[t]);   // deg >= 1 (self-loop)
    dinv[node] = di;
    float4 xv = ((const float4*)x)[node];
    ((float4*)xd)[node] = make_float4(xv.x*di, xv.y*di, xv.z*di, xv.w*di);
  }
}

// ---------------- raw-input aggregation: y4 = D(A_e xd + xd) ----------------
// thread per node; per edge ONE float4 gather from the 800KB xd table

__global__ void k_agg4(const int* __restrict__ rowS, const int* __restrict__ rowE,
                       const u32* __restrict__ packed, const float* __restrict__ xd,
                       const float* __restrict__ dinv, float* __restrict__ y4, int n){
  int i = blockIdx.x*256 + threadIdx.x;
  if (i >= n) return;
  float4 self = ((const float4*)xd)[i];
  float ax = self.x, ay = self.y, az = self.z, aw = self.w;
  int end = rowE[i];
  for (int p = rowS[i]; p < end; ++p){
    u32 v = packed[p];
    float w = __half2float(__ushort_as_half((unsigned short)(v >> 16)));
    float4 xs = ((const float4*)xd)[v & 0xFFFF];
    ax = fmaf(w, xs.x, ax);
    ay = fmaf(w, xs.y, ay);
    az = fmaf(w, xs.z, az);
    aw = fmaf(w, xs.w, aw);
  }
  float di = dinv[i];
  ((float4*)y4)[i] = make_float4(ax*di, ay*di, az*di, aw*di);
}

// ---------------- fused conv1 + relu + conv2-matmul (MFMA) + D-scale ----------
// h1 = y4@W0 + b0 (computed per-lane straight into A-fragments), relu,
// u = relu(h1)@W1 via 8x mfma_f32_16x16x32_f16, out = dinv_row * u (fp16).
// W1 in 8 NAMED B-fragments; W0 cols/b0 in const-indexed unrolled arrays.
// Layouts (HW-verified): A[m=lane&15][k=quad*8+j]; B[k=quad*8+j][col=lane&15];
// C/D: col=lane&15, row=quad*4+reg.
template<int FIN>
__global__ __attribute__((amdgpu_waves_per_eu(2, 4)))
void k_conv2_mfma(const float* __restrict__ y4, const float* __restrict__ yx,
                  const float* __restrict__ W0, const float* __restrict__ b0,
                  const float* __restrict__ W1, const float* __restrict__ dinv,
                  __half* __restrict__ out, int n){
  int lane = threadIdx.x & 63;
  int m = lane & 15, q = lane >> 4;
  int wid = (blockIdx.x*256 + threadIdx.x) >> 6;
  int nw = gridDim.x * 4;

  auto ldB = [&](int kk, int ct){
    f16x8 r;
    #pragma unroll
    for (int j = 0; j < 8; ++j)
      r[j] = (_Float16)W1[(kk*32 + q*8 + j)*64 + ct*16 + m];
    return r;
  };
  f16x8 b00 = ldB(0,0), b01 = ldB(0,1), b02 = ldB(0,2), b03 = ldB(0,3);
  f16x8 b10 = ldB(1,0), b11 = ldB(1,1), b12 = ldB(1,2), b13 = ldB(1,3);

  // W0 columns + bias this lane needs: cols kk*32 + q*8 + j
  float w0c[2][FIN][8];
  float b0c[2][8];
  #pragma unroll
  for (int kk = 0; kk < 2; ++kk){
    #pragma unroll
    for (int j = 0; j < 8; ++j) b0c[kk][j] = b0[kk*32 + q*8 + j];
    #pragma unroll
    for (int c = 0; c < FIN; ++c)
      #pragma unroll
      for (int j = 0; j < 8; ++j)
        w0c[kk][c][j] = W0[c*64 + kk*32 + q*8 + j];
  }

  int ntiles = n >> 4;                         // 50000 = 16*3125 exactly
  for (int tile = wid; tile < ntiles; tile += nw){
    int base = tile << 4;
    float4 yv = ((const float4*)y4)[base + m];
    float y5 = 0.f;
    if constexpr (FIN == 5) y5 = yx[base + m];
    f16x8 a0, a1;
    #pragma unroll
    for (int j = 0; j < 8; ++j){
      float h0 = b0c[0][j], h1 = b0c[1][j];
      h0 = fmaf(yv.x, w0c[0][0][j], h0);  h1 = fmaf(yv.x, w0c[1][0][j], h1);
      h0 = fmaf(yv.y, w0c[0][1][j], h0);  h1 = fmaf(yv.y, w0c[1][1][j], h1);
      h0 = fmaf(yv.z, w0c[0][2][j], h0);  h1 = fmaf(yv.z, w0c[1][2][j], h1);
      h0 = fmaf(yv.w, w0c[0][3][j], h0);  h1 = fmaf(yv.w, w0c[1][3][j], h1);
      if constexpr (FIN == 5){
        h0 = fmaf(y5, w0c[0][4][j], h0);  h1 = fmaf(y5, w0c[1][4][j], h1);
      }
      a0[j] = (_Float16)fmaxf(h0, 0.f);    // relu(h1) -> A fragment
      a1[j] = (_Float16)fmaxf(h1, 0.f);
    }
    f32x4 c0 = {0,0,0,0}, c1 = {0,0,0,0}, c2 = {0,0,0,0}, c3 = {0,0,0,0};
    c0 = __builtin_amdgcn_mfma_f32_16x16x32_f16(a0, b00, c0, 0, 0, 0);
    c0 = __builtin_amdgcn_mfma_f32_16x16x32_f16(a1, b10, c0, 0, 0, 0);
    c1 = __builtin_amdgcn_mfma_f32_16x16x32_f16(a0, b01, c1, 0, 0, 0);
    c1 = __builtin_amdgcn_mfma_f32_16x16x32_f16(a1, b11, c1, 0, 0, 0);
    c2 = __builtin_amdgcn_mfma_f32_16x16x32_f16(a0, b02, c2, 0, 0, 0);
    c2 = __builtin_amdgcn_mfma_f32_16x16x32_f16(a1, b12, c2, 0, 0, 0);
    c3 = __builtin_amdgcn_mfma_f32_16x16x32_f16(a0, b03, c3, 0, 0, 0);
    c3 = __builtin_amdgcn_mfma_f32_16x16x32_f16(a1, b13, c3, 0, 0, 0);

    float4 dv = ((const float4*)dinv)[tile*4 + q];   // rows base+q*4 .. +3
    float dvr[4] = {dv.x, dv.y, dv.z, dv.w};
    auto st = [&](const f32x4& c, int ct){
      int ft = ct*16 + m;                      // feature = col
      #pragma unroll
      for (int r = 0; r < 4; ++r)              // node = row = base + q*4 + r
        out[(size_t)(base + q*4 + r)*64 + ft] = __float2half(c[r]*dvr[r]);
    };
    st(c0, 0); st(c1, 1); st(c2, 2); st(c3, 3);
  }
}

// ---------------- fused conv2-agg + bias + relu + @W2 + D-scale ----------------
// one wave per node; lane = (edge parity ep, feature-pair f2).
// Poisson(32) degree: whole edge list via zero-padded FULLY UNROLLED block
// (~16 gathers in flight; runtime loop kept ~1 -> 59us latency chain, r9).
__global__ __attribute__((amdgpu_waves_per_eu(4, 8)))
void k_agg64f(const int* __restrict__ rowS, const int* __restrict__ rowE,
              const u32* __restrict__ packed, const __half* __restrict__ xw,
              const float* __restrict__ dinv, const float* __restrict__ b,
              const float* __restrict__ W2, float* __restrict__ shat, int n){
  int tid = blockIdx.x*256 + threadIdx.x;
  int node = tid >> 6, lane = tid & 63;
  if (node >= n) return;
  int f2 = lane & 31, ep = lane >> 5;
  const __half2* xw2 = (const __half2*)xw;
  float ax = 0.f, ay = 0.f;
  int p = rowS[node], end = rowE[node];

  auto proc = [&](u32 myv, int t){
    u32 v0 = __builtin_amdgcn_readlane(myv, 2*t);
    u32 v1 = __builtin_amdgcn_readlane(myv, 2*t + 1);
    u32 v = ep ? v1 : v0;
    int s = v & 0xFFFF;
    float w = __half2float(__ushort_as_half((unsigned short)(v >> 16)));
    float2 xf = __half22float2(xw2[s*32 + f2]);
    ax = fmaf(w, xf.x, ax);
    ay = fmaf(w, xf.y, ay);
  };

  // rare path: degree >= 64
  for (; p + 64 <= end; p += 64){
    u32 myv = __builtin_nontemporal_load(&packed[p + lane]);
    #pragma unroll
    for (int t = 0; t < 32; ++t) proc(myv, t);
  }
  // common path: entire (remaining) list in one padded straight-line block
  int rem = end - p;                        // 0..63
  if (rem > 0){
    u32 myv = (lane < rem) ? packed[p + lane] : 0u;   // pad: s=0,w=0 -> adds 0
    #pragma unroll
    for (int t = 0; t < 16; ++t) proc(myv, t);
    if (rem > 32){
      #pragma unroll
      for (int t = 16; t < 32; ++t) proc(myv, t);
    }
  }

  ax += __shfl_xor(ax, 32, 64);                 // combine even/odd edge partials
  ay += __shfl_xor(ay, 32, 64);
  float di = dinv[node];
  float2 sf = __half22float2(xw2[(size_t)node*32 + f2]);   // self term u_hat[d]
  float hx = (ax + sf.x)*di + b[2*f2];
  float hy = (ay + sf.y)*di + b[2*f2 + 1];
  float2 w2 = ((const float2*)W2)[f2];
  float part = fmaxf(hx, 0.f)*w2.x + fmaxf(hy, 0.f)*w2.y;
  part += __shfl_xor(part, 16, 64);             // reduce 32 feature-pairs
  part += __shfl_xor(part, 8, 64);
  part += __shfl_xor(part, 4, 64);
  part += __shfl_xor(part, 2, 64);
  part += __shfl_xor(part, 1, 64);
  if (lane == 0) shat[node] = part * di;        // pre-scaled for next agg
}

// ---------------- scalar aggs: half-wave (32 lanes) per node ----------------

// conv3-agg of s_hat + bias + Linear(1,1) -> xsol (true) and xsol_hat
__global__ void k_agg1_xsol(const int* __restrict__ rowS, const int* __restrict__ rowE,
                            const u32* __restrict__ packed, const float* __restrict__ shat,
                            const float* __restrict__ dinv, const float* __restrict__ b,
                            const float* __restrict__ Wl, const float* __restrict__ bl,
                            float* __restrict__ xsol, float* __restrict__ xsolh, int n){
  int tid = blockIdx.x*256 + threadIdx.x;
  int node = tid >> 5, l = tid & 31;
  if (node >= n) return;
  int beg = rowS[node], end = rowE[node];
  float acc = 0.f;
  for (int p = beg + l; p < end; p += 32){
    u32 v = packed[p];
    float w = __half2float(__ushort_as_half((unsigned short)(v >> 16)));
    acc = fmaf(w, shat[v & 0xFFFF], acc);
  }
  acc += __shfl_xor(acc, 16, 64);   // xor<32 stays within the half
  acc += __shfl_xor(acc, 8, 64);
  acc += __shfl_xor(acc, 4, 64);
  acc += __shfl_xor(acc, 2, 64);
  acc += __shfl_xor(acc, 1, 64);
  if (l == 0){
    float di = dinv[node];
    float h = (acc + shat[node])*di + b[0];
    float v = h*Wl[0] + bl[0];
    xsol[node]  = v;
    xsolh[node] = v*di;
  }
}

// yx = dinv*( sum ew*xsolh[s] + xsolh[d] )  (5th channel of agg5(cat(x,xsol)))
__global__ void k_agg1s(const int* __restrict__ rowS, const int* __restrict__ rowE,
                        const u32* __restrict__ packed, const float* __restrict__ xsh,
                        const float* __restrict__ dinv, float* __restrict__ yx, int n){
  int tid = blockIdx.x*256 + threadIdx.x;
  int node = tid >> 5, l = tid & 31;
  if (node >= n) return;
  int beg = rowS[node], end = rowE[node];
  float acc = 0.f;
  for (int p = beg + l; p < end; p += 32){
    u32 v = packed[p];
    float w = __half2float(__ushort_as_half((unsigned short)(v >> 16)));
    acc = fmaf(w, xsh[v & 0xFFFF], acc);
  }
  acc += __shfl_xor(acc, 16, 64);
  acc += __shfl_xor(acc, 8, 64);
  acc += __shfl_xor(acc, 4, 64);
  acc += __shfl_xor(acc, 2, 64);
  acc += __shfl_xor(acc, 1, 64);
  if (l == 0)
    yx[node] = (acc + xsh[node]) * dinv[node];
}

// conv3-agg + bias + Linear(1,1) + sigmoid + gated residual combine
__global__ void k_agg1_final(const int* __restrict__ rowS, const int* __restrict__ rowE,
                             const u32* __restrict__ packed, const float* __restrict__ shat,
                             const float* __restrict__ dinv, const float* __restrict__ b,
                             const float* __restrict__ Wl, const float* __restrict__ bl,
                             const float* __restrict__ xsol, const float* __restrict__ x,
                             float* __restrict__ out, int n){
  int tid = blockIdx.x*256 + threadIdx.x;
  int node = tid >> 5, l = tid & 31;
  if (node >= n) return;
  int beg = rowS[node], end = rowE[node];
  float acc = 0.f;
  for (int p = beg + l; p < end; p += 32){
    u32 v = packed[p];
    float w = __half2float(__ushort_as_half((unsigned short)(v >> 16)));
    acc = fmaf(w, shat[v & 0xFFFF], acc);
  }
  acc += __shfl_xor(acc, 16, 64);
  acc += __shfl_xor(acc, 8, 64);
  acc += __shfl_xor(acc, 4, 64);
  acc += __shfl_xor(acc, 2, 64);
  acc += __shfl_xor(acc, 1, 64);
  if (l == 0){
    float di = dinv[node];
    float g = ((acc + shat[node])*di + b[0])*Wl[0] + bl[0];
    float gamma = 1.f / (1.f + expf(-g));
    float xl = x[node*4+3];
    out[node]     = xl + gamma*(xsol[node] - xl);
    out[n + node] = gamma;
  }
}

// ---------------- launch ----------------

extern "C" void kernel_launch(void* const* d_in, const int* in_sizes, int n_in,
                              void* d_out, int out_size, void* d_ws, size_t ws_size,
                              hipStream_t stream){
  const float* x   = (const float*)d_in[0];
  const int*   ei  = (const int*)d_in[1];
  const float* ew  = (const float*)d_in[2];
  const float* oW0 = (const float*)d_in[3];
  const float* ob0 = (const float*)d_in[4];
  const float* oW1 = (const float*)d_in[5];
  const float* ob1 = (const float*)d_in[6];
  const float* oW2 = (const float*)d_in[7];
  const float* ob2 = (const float*)d_in[8];
  const float* oWl = (const float*)d_in[9];
  const float* obl = (const float*)d_in[10];
  const float* gW0 = (const float*)d_in[11];
  const float* gb0 = (const float*)d_in[12];
  const float* gW1 = (const float*)d_in[13];
  const float* gb1 = (const float*)d_in[14];
  const float* gW2 = (const float*)d_in[15];
  const float* gb2 = (const float*)d_in[16];
  const float* gWl = (const float*)d_in[17];
  const float* gbl = (const float*)d_in[18];

  const int n = NN, e = NE;
  const int* src = ei;
  const int* dst = ei + e;

  // workspace layout (8B-aligned blocks first)
  char* wsb = (char*)d_ws;
  int2*  seL    = (int2*)wsb;      wsb += (size_t)NBK*CAP*sizeof(int2);  // 14.5 MB
  u32*   packed = (u32*)wsb;       wsb += (size_t)NBK*CAP*4;             // 7.2 MB
  __half* bufA  = (__half*)wsb;    wsb += (size_t)n*64*2;                // 6.4 MB (u_hat)
  float* y4     = (float*)wsb;     wsb += (size_t)n*4*4;                 // 800 KB
  float* xd     = (float*)wsb;     wsb += (size_t)n*4*4;                 // 800 KB
  int*   rowS   = (int*)wsb;       wsb += (size_t)n*4;
  int*   rowE   = (int*)wsb;       wsb += (size_t)n*4;
  int*   bcur   = (int*)wsb;       wsb += 256*4;
  float* dinv   = (float*)wsb;     wsb += (size_t)n*4;
  float* shat   = (float*)wsb;     wsb += (size_t)n*4;
  float* xsol   = (float*)wsb;     wsb += (size_t)n*4;
  float* xsolh  = (float*)wsb;     wsb += (size_t)n*4;
  float* yx     = (float*)wsb;     wsb += (size_t)n*4;

  dim3 b256(256);
  int gn  = cdiv(n, 256);          // 196
  int gw  = cdiv(n*64, 256);       // 12500 (wave-per-node kernels)
  int gw2 = cdiv(n*32, 256);       // 6250  (half-wave-per-node kernels)
  int gb  = cdiv(e, EPB);          // 391
  int gxm = 512;                   // MFMA transform grid

  // ---- CSR build (fixed-capacity bins; no count pre-pass, no scan) ----
  hipMemsetAsync(bcur, 0, 256*4, stream);
  k_bucket    <<<gb,  b256, 0, stream>>>(src, dst, ew, bcur, seL, e);
  k_csr_bucket<<<NBK, b256, 0, stream>>>(bcur, seL, x, rowS, rowE, packed, dinv, xd, n);

  // shared raw-x aggregation (both towers' layer 1)
  k_agg4      <<<gn,  b256, 0, stream>>>(rowS, rowE, packed, xd, dinv, y4, n);

  // ---- optim tower ----
  k_conv2_mfma<4><<<gxm, b256, 0, stream>>>(y4, nullptr, oW0, ob0, oW1, dinv, bufA, n);
  k_agg64f       <<<gw,  b256, 0, stream>>>(rowS, rowE, packed, bufA, dinv, ob1, oW2, shat, n);
  k_agg1_xsol    <<<gw2, b256, 0, stream>>>(rowS, rowE, packed, shat, dinv, ob2, oWl, obl, xsol, xsolh, n);

  // ---- gamma tower: agg5(cat(x,xsol)) = [y4 | agg1(xsol)] ----
  k_agg1s        <<<gw2, b256, 0, stream>>>(rowS, rowE, packed, xsolh, dinv, yx, n);
  k_conv2_mfma<5><<<gxm, b256, 0, stream>>>(y4, yx, gW0, gb0, gW1, dinv, bufA, n);
  k_agg64f       <<<gw,  b256, 0, stream>>>(rowS, rowE, packed, bufA, dinv, gb1, gW2, shat, n);
  k_agg1_final   <<<gw2, b256, 0, stream>>>(rowS, rowE, packed, shat, dinv, gb2, gWl, gbl, xsol, x, (float*)d_out, n);
}

// Round 14
// 293.350 us; speedup vs baseline: 2.8313x; 1.0055x over previous
//
#include <hip/hip_runtime.h>
#include <hip/hip_fp16.h>
#include <math.h>

#define NN 50000
#define NE 1600000
#define NBK 196          // buckets of 256 dst-nodes: cdiv(50000,256)
#define EPB 4096         // edges per block in k_bucket (= 16 per thread)
#define CAP 9216         // per-bucket capacity; mean 8163, sigma~90 -> 11σ margin

typedef unsigned int u32;
typedef _Float16 f16x8 __attribute__((ext_vector_type(8)));
typedef float f32x4 __attribute__((ext_vector_type(4)));

static inline int cdiv(int a, int b){ return (a + b - 1) / b; }

// D-scaling convention: every stored feature tensor is S = dinv (.) H.
// GCN layer: H' = dinv_d * ( sum_e ew*S[src] + S[d] ) + b; relu commutes (dinv>0).
// Edges carry RAW fp16(ew). Buckets are fixed-capacity bins (no global scan).

// ---------------- CSR build ----------------

// single pass: hist (dst kept in regs) -> reserve -> scatter into padded bins
__global__ void k_bucket(const int* __restrict__ src, const int* __restrict__ dst,
                         const float* __restrict__ ew, int* __restrict__ bcur,
                         int2* __restrict__ seL, int e){
  __shared__ int h[NBK], base[NBK], curL[NBK];
  int t = threadIdx.x;
  for (int b = t; b < NBK; b += 256){ h[b] = 0; curL[b] = 0; }
  __syncthreads();
  int beg = blockIdx.x*EPB;
  int d[16];
  #pragma unroll
  for (int i = 0; i < 16; ++i){
    int idx = beg + t + i*256;
    d[i] = (idx < e) ? dst[idx] : -1;
    if (d[i] >= 0) atomicAdd(&h[d[i] >> 8], 1);
  }
  __syncthreads();
  for (int b = t; b < NBK; b += 256)
    if (h[b] > 0) base[b] = b*CAP + atomicAdd(&bcur[b], h[b]);   // bcur zero-init
  __syncthreads();
  #pragma unroll
  for (int i = 0; i < 16; ++i){
    int idx = beg + t + i*256;
    if (idx >= e) continue;
    int dd = d[i], b = dd >> 8;
    int pos = base[b] + atomicAdd(&curL[b], 1);
    seL[pos] = make_int2(((dd & 255) << 16) | src[idx], __float_as_int(ew[idx]));
  }
}

// one block per bucket; edges STAGED IN LDS (<= 73.7KB), read from global ONCE.
// hist+wsum folded into the load pass; scan+scatter+deg in LDS.
// packed entry: lo16 = src, hi16 = fp16(ew). Emits rowS/rowE, dinv, xd=dinv(.)x.
__global__ void k_csr_bucket(const int* __restrict__ bcur, const int2* __restrict__ seL,
                             const float* __restrict__ x, int* __restrict__ rowS,
                             int* __restrict__ rowE, u32* __restrict__ packed,
                             float* __restrict__ dinv, float* __restrict__ xd, int n){
  __shared__ int2 eb[CAP];                       // 73728 B
  __shared__ int hist[256], sh[256], cur[256];
  __shared__ float wsum[256];
  int b = blockIdx.x, t = threadIdx.x;
  int cnt = bcur[b];
  int ebeg = b*CAP;
  hist[t] = 0; wsum[t] = 0.f;
  __syncthreads();
  for (int i = t; i < cnt; i += 256){            // load + hist + wsum, one pass
    int2 u = seL[ebeg + i];
    eb[i] = u;
    int d = u.x >> 16;
    atomicAdd(&hist[d], 1);
    atomicAdd(&wsum[d], __int_as_float(u.y));
  }
  __syncthreads();
  int v = hist[t];
  sh[t] = v; __syncthreads();
  for (int o = 1; o < 256; o <<= 1){
    int u = (t >= o) ? sh[t-o] : 0;
    __syncthreads();
    sh[t] += u;
    __syncthreads();
  }
  int rs = ebeg + sh[t] - v;
  int node = b*256 + t;
  if (node < n){ rowS[node] = rs; rowE[node] = rs + v; }
  cur[t] = rs;
  __syncthreads();
  for (int i = t; i < cnt; i += 256){            // scatter from LDS
    int2 u = eb[i];
    int d = u.x >> 16;
    int pos = atomicAdd(&cur[d], 1);
    packed[pos] = (u32)(u.x & 0xFFFF) |
                  ((u32)__half_as_ushort(__float2half(__int_as_float(u.y))) << 16);
  }
  __syncthreads();
  if (node < n){
    float di = rsqrtf(1.f + wsum[t]);   // deg >= 1 (self-loop)
    dinv[node] = di;
    float4 xv = ((const float4*)x)[node];
    ((float4*)xd)[node] = make_float4(xv.x*di, xv.y*di, xv.z*di, xv.w*di);
  }
}

// ---------------- raw-input aggregation: y4 = D(A_e xd + xd) ----------------
// thread per node; per edge ONE float4 gather from the 800KB xd table

__global__ void k_agg4(const int* __restrict__ rowS, const int* __restrict__ rowE,
                       const u32* __restrict__ packed, const float* __restrict__ xd,
                       const float* __restrict__ dinv, float* __restrict__ y4, int n){
  int i = blockIdx.x*256 + threadIdx.x;
  if (i >= n) return;
  float4 self = ((const float4*)xd)[i];
  float ax = self.x, ay = self.y, az = self.z, aw = self.w;
  int end = rowE[i];
  for (int p = rowS[i]; p < end; ++p){
    u32 v = packed[p];
    float w = __half2float(__ushort_as_half((unsigned short)(v >> 16)));
    float4 xs = ((const float4*)xd)[v & 0xFFFF];
    ax = fmaf(w, xs.x, ax);
    ay = fmaf(w, xs.y, ay);
    az = fmaf(w, xs.z, az);
    aw = fmaf(w, xs.w, aw);
  }
  float di = dinv[i];
  ((float4*)y4)[i] = make_float4(ax*di, ay*di, az*di, aw*di);
}

// ---------------- fused conv1 + relu + conv2-matmul (MFMA) + D-scale ----------
// h1 = y4@W0 + b0 per-lane into A-fragments, relu, u = relu(h1)@W1 via 8x
// mfma_f32_16x16x32_f16, out = dinv_row * u (fp16).
// FIN==5: the 5th channel yx = dinv*(sum ew*xsolh[src] + xsolh[d]) is computed
// IN-KERNEL by 4 q-lanes per node (stride-4 edge split, masked unroll, shfl
// reduce over q) -- deletes the standalone k_agg1s launch + yx round-trip.
// Layouts (HW-verified): A[m=lane&15][k=quad*8+j]; B[k=quad*8+j][col=lane&15];
// C/D: col=lane&15, row=quad*4+reg.
template<int FIN>
__global__ __attribute__((amdgpu_waves_per_eu(2, 4)))
void k_conv2_mfma(const float* __restrict__ y4,
                  const int* __restrict__ rowS, const int* __restrict__ rowE,
                  const u32* __restrict__ packed, const float* __restrict__ xsolh,
                  const float* __restrict__ W0, const float* __restrict__ b0,
                  const float* __restrict__ W1, const float* __restrict__ dinv,
                  __half* __restrict__ out, int n){
  int lane = threadIdx.x & 63;
  int m = lane & 15, q = lane >> 4;
  int wid = (blockIdx.x*256 + threadIdx.x) >> 6;
  int nw = gridDim.x * 4;

  auto ldB = [&](int kk, int ct){
    f16x8 r;
    #pragma unroll
    for (int j = 0; j < 8; ++j)
      r[j] = (_Float16)W1[(kk*32 + q*8 + j)*64 + ct*16 + m];
    return r;
  };
  f16x8 b00 = ldB(0,0), b01 = ldB(0,1), b02 = ldB(0,2), b03 = ldB(0,3);
  f16x8 b10 = ldB(1,0), b11 = ldB(1,1), b12 = ldB(1,2), b13 = ldB(1,3);

  // W0 columns + bias this lane needs: cols kk*32 + q*8 + j
  float w0c[2][FIN][8];
  float b0c[2][8];
  #pragma unroll
  for (int kk = 0; kk < 2; ++kk){
    #pragma unroll
    for (int j = 0; j < 8; ++j) b0c[kk][j] = b0[kk*32 + q*8 + j];
    #pragma unroll
    for (int c = 0; c < FIN; ++c)
      #pragma unroll
      for (int j = 0; j < 8; ++j)
        w0c[kk][c][j] = W0[c*64 + kk*32 + q*8 + j];
  }

  int ntiles = n >> 4;                         // 50000 = 16*3125 exactly
  for (int tile = wid; tile < ntiles; tile += nw){
    int base = tile << 4;
    float4 yv = ((const float4*)y4)[base + m];
    float y5 = 0.f;
    if constexpr (FIN == 5){
      // cooperative scalar agg: 4 q-lanes split node (base+m)'s edges stride-4
      int node = base + m;
      int p0 = rowS[node] + q, end = rowE[node];
      float acc = 0.f;
      auto eproc = [&](int p){
        u32 v = (p < end) ? packed[p] : 0u;     // pad: s=0,w=0 -> adds 0
        float w = __half2float(__ushort_as_half((unsigned short)(v >> 16)));
        acc = fmaf(w, xsolh[v & 0xFFFF], acc);
      };
      #pragma unroll
      for (int tt = 0; tt < 8; ++tt) eproc(p0 + 4*tt);       // edges 0..31
      if (p0 + 32 < end){
        #pragma unroll
        for (int tt = 8; tt < 16; ++tt) eproc(p0 + 4*tt);    // edges 32..63
      }
      for (int p = p0 + 64; p < end; p += 4) eproc(p);       // rare deg>64
      acc += __shfl_xor(acc, 16, 64);          // reduce over q (m preserved)
      acc += __shfl_xor(acc, 32, 64);
      y5 = (acc + xsolh[node]) * dinv[node];
    }
    f16x8 a0, a1;
    #pragma unroll
    for (int j = 0; j < 8; ++j){
      float h0 = b0c[0][j], h1 = b0c[1][j];
      h0 = fmaf(yv.x, w0c[0][0][j], h0);  h1 = fmaf(yv.x, w0c[1][0][j], h1);
      h0 = fmaf(yv.y, w0c[0][1][j], h0);  h1 = fmaf(yv.y, w0c[1][1][j], h1);
      h0 = fmaf(yv.z, w0c[0][2][j], h0);  h1 = fmaf(yv.z, w0c[1][2][j], h1);
      h0 = fmaf(yv.w, w0c[0][3][j], h0);  h1 = fmaf(yv.w, w0c[1][3][j], h1);
      if constexpr (FIN == 5){
        h0 = fmaf(y5, w0c[0][4][j], h0);  h1 = fmaf(y5, w0c[1][4][j], h1);
      }
      a0[j] = (_Float16)fmaxf(h0, 0.f);    // relu(h1) -> A fragment
      a1[j] = (_Float16)fmaxf(h1, 0.f);
    }
    f32x4 c0 = {0,0,0,0}, c1 = {0,0,0,0}, c2 = {0,0,0,0}, c3 = {0,0,0,0};
    c0 = __builtin_amdgcn_mfma_f32_16x16x32_f16(a0, b00, c0, 0, 0, 0);
    c0 = __builtin_amdgcn_mfma_f32_16x16x32_f16(a1, b10, c0, 0, 0, 0);
    c1 = __builtin_amdgcn_mfma_f32_16x16x32_f16(a0, b01, c1, 0, 0, 0);
    c1 = __builtin_amdgcn_mfma_f32_16x16x32_f16(a1, b11, c1, 0, 0, 0);
    c2 = __builtin_amdgcn_mfma_f32_16x16x32_f16(a0, b02, c2, 0, 0, 0);
    c2 = __builtin_amdgcn_mfma_f32_16x16x32_f16(a1, b12, c2, 0, 0, 0);
    c3 = __builtin_amdgcn_mfma_f32_16x16x32_f16(a0, b03, c3, 0, 0, 0);
    c3 = __builtin_amdgcn_mfma_f32_16x16x32_f16(a1, b13, c3, 0, 0, 0);

    float4 dv = ((const float4*)dinv)[tile*4 + q];   // rows base+q*4 .. +3
    float dvr[4] = {dv.x, dv.y, dv.z, dv.w};
    auto st = [&](const f32x4& c, int ct){
      int ft = ct*16 + m;                      // feature = col
      #pragma unroll
      for (int r = 0; r < 4; ++r)              // node = row = base + q*4 + r
        out[(size_t)(base + q*4 + r)*64 + ft] = __float2half(c[r]*dvr[r]);
    };
    st(c0, 0); st(c1, 1); st(c2, 2); st(c3, 3);
  }
}

// ---------------- fused conv2-agg + bias + relu + @W2 + D-scale ----------------
// one wave per node; lane = (edge parity ep, feature-pair f2).
// Poisson(32) degree: whole edge list via zero-padded FULLY UNROLLED block
// (~16 gathers in flight; runtime loop kept ~1 -> 59us latency chain, r9).
__global__ __attribute__((amdgpu_waves_per_eu(4, 8)))
void k_agg64f(const int* __restrict__ rowS, const int* __restrict__ rowE,
              const u32* __restrict__ packed, const __half* __restrict__ xw,
              const float* __restrict__ dinv, const float* __restrict__ b,
              const float* __restrict__ W2, float* __restrict__ shat, int n){
  int tid = blockIdx.x*256 + threadIdx.x;
  int node = tid >> 6, lane = tid & 63;
  if (node >= n) return;
  int f2 = lane & 31, ep = lane >> 5;
  const __half2* xw2 = (const __half2*)xw;
  float ax = 0.f, ay = 0.f;
  int p = rowS[node], end = rowE[node];

  auto proc = [&](u32 myv, int t){
    u32 v0 = __builtin_amdgcn_readlane(myv, 2*t);
    u32 v1 = __builtin_amdgcn_readlane(myv, 2*t + 1);
    u32 v = ep ? v1 : v0;
    int s = v & 0xFFFF;
    float w = __half2float(__ushort_as_half((unsigned short)(v >> 16)));
    float2 xf = __half22float2(xw2[s*32 + f2]);
    ax = fmaf(w, xf.x, ax);
    ay = fmaf(w, xf.y, ay);
  };

  // rare path: degree >= 64
  for (; p + 64 <= end; p += 64){
    u32 myv = __builtin_nontemporal_load(&packed[p + lane]);
    #pragma unroll
    for (int t = 0; t < 32; ++t) proc(myv, t);
  }
  // common path: entire (remaining) list in one padded straight-line block
  int rem = end - p;                        // 0..63
  if (rem > 0){
    u32 myv = (lane < rem) ? packed[p + lane] : 0u;   // pad: s=0,w=0 -> adds 0
    #pragma unroll
    for (int t = 0; t < 16; ++t) proc(myv, t);
    if (rem > 32){
      #pragma unroll
      for (int t = 16; t < 32; ++t) proc(myv, t);
    }
  }

  ax += __shfl_xor(ax, 32, 64);                 // combine even/odd edge partials
  ay += __shfl_xor(ay, 32, 64);
  float di = dinv[node];
  float2 sf = __half22float2(xw2[(size_t)node*32 + f2]);   // self term u_hat[d]
  float hx = (ax + sf.x)*di + b[2*f2];
  float hy = (ay + sf.y)*di + b[2*f2 + 1];
  float2 w2 = ((const float2*)W2)[f2];
  float part = fmaxf(hx, 0.f)*w2.x + fmaxf(hy, 0.f)*w2.y;
  part += __shfl_xor(part, 16, 64);             // reduce 32 feature-pairs
  part += __shfl_xor(part, 8, 64);
  part += __shfl_xor(part, 4, 64);
  part += __shfl_xor(part, 2, 64);
  part += __shfl_xor(part, 1, 64);
  if (lane == 0) shat[node] = part * di;        // pre-scaled for next agg
}

// ---------------- scalar aggs: half-wave (32 lanes) per node ----------------

// conv3-agg of s_hat + bias + Linear(1,1) -> xsol (true) and xsol_hat
__global__ void k_agg1_xsol(const int* __restrict__ rowS, const int* __restrict__ rowE,
                            const u32* __restrict__ packed, const float* __restrict__ shat,
                            const float* __restrict__ dinv, const float* __restrict__ b,
                            const float* __restrict__ Wl, const float* __restrict__ bl,
                            float* __restrict__ xsol, float* __restrict__ xsolh, int n){
  int tid = blockIdx.x*256 + threadIdx.x;
  int node = tid >> 5, l = tid & 31;
  if (node >= n) return;
  int beg = rowS[node], end = rowE[node];
  float acc = 0.f;
  for (int p = beg + l; p < end; p += 32){
    u32 v = packed[p];
    float w = __half2float(__ushort_as_half((unsigned short)(v >> 16)));
    acc = fmaf(w, shat[v & 0xFFFF], acc);
  }
  acc += __shfl_xor(acc, 16, 64);   // xor<32 stays within the half
  acc += __shfl_xor(acc, 8, 64);
  acc += __shfl_xor(acc, 4, 64);
  acc += __shfl_xor(acc, 2, 64);
  acc += __shfl_xor(acc, 1, 64);
  if (l == 0){
    float di = dinv[node];
    float h = (acc + shat[node])*di + b[0];
    float v = h*Wl[0] + bl[0];
    xsol[node]  = v;
    xsolh[node] = v*di;
  }
}

// conv3-agg + bias + Linear(1,1) + sigmoid + gated residual combine
__global__ void k_agg1_final(const int* __restrict__ rowS, const int* __restrict__ rowE,
                             const u32* __restrict__ packed, const float* __restrict__ shat,
                             const float* __restrict__ dinv, const float* __restrict__ b,
                             const float* __restrict__ Wl, const float* __restrict__ bl,
                             const float* __restrict__ xsol, const float* __restrict__ x,
                             float* __restrict__ out, int n){
  int tid = blockIdx.x*256 + threadIdx.x;
  int node = tid >> 5, l = tid & 31;
  if (node >= n) return;
  int beg = rowS[node], end = rowE[node];
  float acc = 0.f;
  for (int p = beg + l; p < end; p += 32){
    u32 v = packed[p];
    float w = __half2float(__ushort_as_half((unsigned short)(v >> 16)));
    acc = fmaf(w, shat[v & 0xFFFF], acc);
  }
  acc += __shfl_xor(acc, 16, 64);
  acc += __shfl_xor(acc, 8, 64);
  acc += __shfl_xor(acc, 4, 64);
  acc += __shfl_xor(acc, 2, 64);
  acc += __shfl_xor(acc, 1, 64);
  if (l == 0){
    float di = dinv[node];
    float g = ((acc + shat[node])*di + b[0])*Wl[0] + bl[0];
    float gamma = 1.f / (1.f + expf(-g));
    float xl = x[node*4+3];
    out[node]     = xl + gamma*(xsol[node] - xl);
    out[n + node] = gamma;
  }
}

// ---------------- launch ----------------

extern "C" void kernel_launch(void* const* d_in, const int* in_sizes, int n_in,
                              void* d_out, int out_size, void* d_ws, size_t ws_size,
                              hipStream_t stream){
  const float* x   = (const float*)d_in[0];
  const int*   ei  = (const int*)d_in[1];
  const float* ew  = (const float*)d_in[2];
  const float* oW0 = (const float*)d_in[3];
  const float* ob0 = (const float*)d_in[4];
  const float* oW1 = (const float*)d_in[5];
  const float* ob1 = (const float*)d_in[6];
  const float* oW2 = (const float*)d_in[7];
  const float* ob2 = (const float*)d_in[8];
  const float* oWl = (const float*)d_in[9];
  const float* obl = (const float*)d_in[10];
  const float* gW0 = (const float*)d_in[11];
  const float* gb0 = (const float*)d_in[12];
  const float* gW1 = (const float*)d_in[13];
  const float* gb1 = (const float*)d_in[14];
  const float* gW2 = (const float*)d_in[15];
  const float* gb2 = (const float*)d_in[16];
  const float* gWl = (const float*)d_in[17];
  const float* gbl = (const float*)d_in[18];

  const int n = NN, e = NE;
  const int* src = ei;
  const int* dst = ei + e;

  // workspace layout (8B-aligned blocks first)
  char* wsb = (char*)d_ws;
  int2*  seL    = (int2*)wsb;      wsb += (size_t)NBK*CAP*sizeof(int2);  // 14.5 MB
  u32*   packed = (u32*)wsb;       wsb += (size_t)NBK*CAP*4;             // 7.2 MB
  __half* bufA  = (__half*)wsb;    wsb += (size_t)n*64*2;                // 6.4 MB (u_hat)
  float* y4     = (float*)wsb;     wsb += (size_t)n*4*4;                 // 800 KB
  float* xd     = (float*)wsb;     wsb += (size_t)n*4*4;                 // 800 KB
  int*   rowS   = (int*)wsb;       wsb += (size_t)n*4;
  int*   rowE   = (int*)wsb;       wsb += (size_t)n*4;
  int*   bcur   = (int*)wsb;       wsb += 256*4;
  float* dinv   = (float*)wsb;     wsb += (size_t)n*4;
  float* shat   = (float*)wsb;     wsb += (size_t)n*4;
  float* xsol   = (float*)wsb;     wsb += (size_t)n*4;
  float* xsolh  = (float*)wsb;     wsb += (size_t)n*4;

  dim3 b256(256);
  int gn  = cdiv(n, 256);          // 196
  int gw  = cdiv(n*64, 256);       // 12500 (wave-per-node kernels)
  int gw2 = cdiv(n*32, 256);       // 6250  (half-wave-per-node kernels)
  int gb  = cdiv(e, EPB);          // 391
  int gxm = 512;                   // MFMA transform grid

  // ---- CSR build (fixed-capacity bins; no count pre-pass, no scan) ----
  hipMemsetAsync(bcur, 0, 256*4, stream);
  k_bucket    <<<gb,  b256, 0, stream>>>(src, dst, ew, bcur, seL, e);
  k_csr_bucket<<<NBK, b256, 0, stream>>>(bcur, seL, x, rowS, rowE, packed, dinv, xd, n);

  // shared raw-x aggregation (both towers' layer 1)
  k_agg4      <<<gn,  b256, 0, stream>>>(rowS, rowE, packed, xd, dinv, y4, n);

  // ---- optim tower ----
  k_conv2_mfma<4><<<gxm, b256, 0, stream>>>(y4, rowS, rowE, packed, nullptr,
                                            oW0, ob0, oW1, dinv, bufA, n);
  k_agg64f       <<<gw,  b256, 0, stream>>>(rowS, rowE, packed, bufA, dinv, ob1, oW2, shat, n);
  k_agg1_xsol    <<<gw2, b256, 0, stream>>>(rowS, rowE, packed, shat, dinv, ob2, oWl, obl, xsol, xsolh, n);

  // ---- gamma tower: agg5(cat(x,xsol)) = [y4 | in-kernel agg1(xsolh)] ----
  k_conv2_mfma<5><<<gxm, b256, 0, stream>>>(y4, rowS, rowE, packed, xsolh,
                                            gW0, gb0, gW1, dinv, bufA, n);
  k_agg64f       <<<gw,  b256, 0, stream>>>(rowS, rowE, packed, bufA, dinv, gb1, gW2, shat, n);
  k_agg1_final   <<<gw2, b256, 0, stream>>>(rowS, rowE, packed, shat, dinv, gb2, gWl, gbl, xsol, x, (float*)d_out, n);
}